// Round 13
// baseline (250.811 us; speedup 1.0000x reference)
//
#include <hip/hip_runtime.h>
#include <math.h>

// ---------------------------------------------------------------------------
// MyTopoAgent R13 (base: R12, repacked pipeline):
//  L1 zero U wt-prep | L2 scatter U mfma_c1 | L3 gather_c1 U mark1
//  L4 mfma_c2 U mark2 | L5 gather_v U dual-fp32-GEMM | L6 a1_fused | L7 a2head
//  Long pole first in every grid.  7 launches; critical path ~136 us.
// ---------------------------------------------------------------------------

typedef __attribute__((ext_vector_type(8))) short bf16x8;
typedef __attribute__((ext_vector_type(4))) float f32x4;

__device__ __forceinline__ float wave_reduce_sum(float v){
  #pragma unroll
  for (int o = 32; o > 0; o >>= 1) v += __shfl_xor(v, o);
  return v;
}
__device__ __forceinline__ unsigned short f2bf(float f){
  unsigned int u = __float_as_uint(f);
  u += 0x7FFFu + ((u >> 16) & 1u);
  return (unsigned short)(u >> 16);
}
__device__ __forceinline__ void unpack2(unsigned int u, float& a, float& b){
  a = __uint_as_float(u << 16);
  b = __uint_as_float(u & 0xffff0000u);
}

// ---------------- L1: zero cnt|flag1|flag2|nn  U  bf16 weight prep ----------------
__global__ void k_init(int* __restrict__ p, int nz,
                       const float* __restrict__ W1l, const float* __restrict__ W1r,
                       const float* __restrict__ W2l, const float* __restrict__ W2r,
                       unsigned short* __restrict__ Wt1, unsigned short* __restrict__ Wt2){
  int i = blockIdx.x * blockDim.x + threadIdx.x;
  if (i < nz){
    p[i] = 0;
  } else {
    int r = i - nz;
    if (r < 65536){
      int which = r >> 15;
      int lin = r & 32767;
      const float* Wl = which ? W2l : W1l;
      const float* Wr = which ? W2r : W1r;
      unsigned short* Wt = which ? Wt2 : Wt1;
      int n = lin >> 7, k = lin & 127;
      float v = (n < 128) ? Wl[(size_t)k * 128 + n] : Wr[(size_t)k * 128 + (n - 128)];
      Wt[lin] = f2bf(v);
    }
  }
}

// ---------------- device: MFMA bf16 GEMM block (swapped ops) ----------------
template<bool CVT>
__device__ __forceinline__ void dev_gemm_mfma(
    int rblk, const void* __restrict__ Av, const unsigned short* __restrict__ Wt,
    const float* __restrict__ bl, const float* __restrict__ br,
    unsigned short* __restrict__ XL, unsigned short* __restrict__ XR){
  int w = threadIdx.x >> 6, lane = threadIdx.x & 63;
  int l16 = lane & 15, kg = lane >> 4;
  int rBase = rblk * 64 + w * 16;
  f32x4 acc[16];
  #pragma unroll
  for (int i = 0; i < 16; ++i) acc[i] = (f32x4){0.f, 0.f, 0.f, 0.f};
  #pragma unroll
  for (int ks = 0; ks < 4; ++ks){
    bf16x8 a;
    if constexpr (CVT){
      const float* A = (const float*)Av;
      const float* ap = A + (size_t)(rBase + l16) * 128 + ks * 32 + kg * 8;
      float4 f0 = *(const float4*)ap;
      float4 f1 = *(const float4*)(ap + 4);
      union { bf16x8 v; unsigned short s[8]; } u;
      u.s[0] = f2bf(f0.x); u.s[1] = f2bf(f0.y); u.s[2] = f2bf(f0.z); u.s[3] = f2bf(f0.w);
      u.s[4] = f2bf(f1.x); u.s[5] = f2bf(f1.y); u.s[6] = f2bf(f1.z); u.s[7] = f2bf(f1.w);
      a = u.v;
    } else {
      a = *(const bf16x8*)((const unsigned short*)Av + (size_t)(rBase + l16) * 128 + ks * 32 + kg * 8);
    }
    #pragma unroll
    for (int ct = 0; ct < 16; ++ct){
      bf16x8 wv = *(const bf16x8*)(Wt + (size_t)(ct * 16 + l16) * 128 + ks * 32 + kg * 8);
      acc[ct] = __builtin_amdgcn_mfma_f32_16x16x32_bf16(wv, a, acc[ct], 0, 0, 0);
    }
  }
  int row = rBase + l16;
  #pragma unroll
  for (int ct = 0; ct < 16; ++ct){
    int col = ct * 16 + kg * 4;
    const float* bp = (col < 128) ? (bl + col) : (br + (col - 128));
    float4 bb = *(const float4*)bp;
    unsigned int p0 = (unsigned int)f2bf(acc[ct][0] + bb.x) |
                      ((unsigned int)f2bf(acc[ct][1] + bb.y) << 16);
    unsigned int p1 = (unsigned int)f2bf(acc[ct][2] + bb.z) |
                      ((unsigned int)f2bf(acc[ct][3] + bb.w) << 16);
    unsigned short* dst = (col < 128) ? (XL + (size_t)row * 128 + col)
                                      : (XR + (size_t)row * 128 + (col - 128));
    uint2 pk; pk.x = p0; pk.y = p1;
    *(uint2*)dst = pk;
  }
}

// ---------------- L2: scatter (first)  U  mfma_c1 ----------------
__global__ __launch_bounds__(256) void k_L2(
    const int* __restrict__ ei, int E, int nS,
    int* __restrict__ cnt, int* __restrict__ bucket,
    const float* __restrict__ x, const unsigned short* __restrict__ Wt1,
    const float* __restrict__ c1_bl, const float* __restrict__ c1_br,
    unsigned short* __restrict__ XLb, unsigned short* __restrict__ XRb){
  int bid = blockIdx.x;
  if (bid < nS){
    int e = bid * 256 + threadIdx.x;
    if (e < E){
      int s = ei[e], t = ei[E + e];
      int pos = atomicAdd(&cnt[t], 1);
      if (pos < 64) bucket[(size_t)t * 64 + pos] = s;
    }
  } else {
    dev_gemm_mfma<true>(bid - nS, x, Wt1, c1_bl, c1_br, XLb, XRb);
  }
}

// ---------------- device: frontier marks ----------------
__device__ __forceinline__ void dev_mark1(
    const int* __restrict__ cnt, const int* __restrict__ bucket,
    int* __restrict__ flag1, int* __restrict__ list1, int* __restrict__ n1, int N){
  int p = threadIdx.x;
  if (p >= 32) return;
  int node = (p >> 3) * N + (p & 7);
  if (atomicExch(&flag1[node], 1) == 0) list1[atomicAdd(n1, 1)] = node;  // self
  int deg = min(cnt[node], 64);
  const int* crow = bucket + (size_t)node * 64;
  for (int j = 0; j < deg; ++j){
    int s = crow[j];
    if (atomicExch(&flag1[s], 1) == 0) list1[atomicAdd(n1, 1)] = s;
  }
}
__device__ __forceinline__ void dev_mark2(
    int vbid, int nblk,
    const int* __restrict__ cnt, const int* __restrict__ bucket,
    const int* __restrict__ list1, const int* __restrict__ n1,
    int* __restrict__ flag2, int* __restrict__ list2, int* __restrict__ n2){
  int n = *n1;
  for (int i = vbid * blockDim.x + threadIdx.x; i < n; i += nblk * blockDim.x){
    int node = list1[i];
    if (atomicExch(&flag2[node], 1) == 0) list2[atomicAdd(n2, 1)] = node;  // self
    int deg = min(cnt[node], 64);
    const int* crow = bucket + (size_t)node * 64;
    for (int j = 0; j < deg; ++j){
      int s = crow[j];
      if (atomicExch(&flag2[s], 1) == 0) list2[atomicAdd(n2, 1)] = s;
    }
  }
}

// ---------------- device: bf16 gather (implicit self, quad depth-1) ----------------
template<int MODE>
__device__ __forceinline__ void dev_gather16(
    int gid, int l,
    const unsigned short* __restrict__ XL, const unsigned short* __restrict__ XR,
    const int* __restrict__ cnt, const int* __restrict__ bucket,
    const float* __restrict__ att, const float* __restrict__ bias,
    const float* __restrict__ fcW, const float* __restrict__ fcb,
    void* __restrict__ outp){
  uint4 xu = *(const uint4*)(XR + (size_t)gid * 128 + l * 8);
  float xr[8];
  unpack2(xu.x, xr[0], xr[1]); unpack2(xu.y, xr[2], xr[3]);
  unpack2(xu.z, xr[4], xr[5]); unpack2(xu.w, xr[6], xr[7]);
  float at[8];
  {
    float4 a0 = *(const float4*)(att + l * 8);
    float4 a1 = *(const float4*)(att + l * 8 + 4);
    at[0] = a0.x; at[1] = a0.y; at[2] = a0.z; at[3] = a0.w;
    at[4] = a1.x; at[5] = a1.y; at[6] = a1.z; at[7] = a1.w;
  }
  int deg = min(cnt[gid], 64);
  const int* __restrict__ crow = bucket + (size_t)gid * 64;
  float m = -INFINITY, den = 0.f;
  float acc[8] = {0.f, 0.f, 0.f, 0.f, 0.f, 0.f, 0.f, 0.f};

  auto proc = [&](uint4 u){
    float xl[8];
    unpack2(u.x, xl[0], xl[1]); unpack2(u.y, xl[2], xl[3]);
    unpack2(u.z, xl[4], xl[5]); unpack2(u.w, xl[6], xl[7]);
    float e = 0.f;
    #pragma unroll
    for (int c = 0; c < 8; ++c){
      float v = xl[c] + xr[c];
      v = fmaxf(v, 0.2f * v);
      e = fmaf(v, at[c], e);
    }
    e += __shfl_xor(e, 1, 16);
    e += __shfl_xor(e, 2, 16);
    e += __shfl_xor(e, 4, 16);
    e += __shfl_xor(e, 8, 16);
    if (e > m){
      float sc = __expf(m - e);
      den *= sc;
      #pragma unroll
      for (int c = 0; c < 8; ++c) acc[c] *= sc;
      m = e;
    }
    float p = __expf(e - m);
    den += p;
    #pragma unroll
    for (int c = 0; c < 8; ++c) acc[c] = fmaf(p, xl[c], acc[c]);
  };

  // self edge
  proc(*(const uint4*)(XL + (size_t)gid * 128 + l * 8));

  // depth-1 quad rotation over real edges
  int nq = deg >> 2;
  int j = 0;
  if (nq > 0){
    uint4 r0, r1, r2, r3;
    {
      int s0 = crow[0], s1 = crow[1], s2 = crow[2], s3 = crow[3];
      r0 = *(const uint4*)(XL + (size_t)s0 * 128 + l * 8);
      r1 = *(const uint4*)(XL + (size_t)s1 * 128 + l * 8);
      r2 = *(const uint4*)(XL + (size_t)s2 * 128 + l * 8);
      r3 = *(const uint4*)(XL + (size_t)s3 * 128 + l * 8);
    }
    for (int q = 1;; ++q){
      bool more = (q < nq);
      uint4 n0, n1, n2, n3;
      if (more){
        int b4 = q * 4;
        int t0 = crow[b4 + 0], t1 = crow[b4 + 1], t2 = crow[b4 + 2], t3 = crow[b4 + 3];
        n0 = *(const uint4*)(XL + (size_t)t0 * 128 + l * 8);
        n1 = *(const uint4*)(XL + (size_t)t1 * 128 + l * 8);
        n2 = *(const uint4*)(XL + (size_t)t2 * 128 + l * 8);
        n3 = *(const uint4*)(XL + (size_t)t3 * 128 + l * 8);
      }
      proc(r0); proc(r1); proc(r2); proc(r3);
      if (!more) break;
      r0 = n0; r1 = n1; r2 = n2; r3 = n3;
    }
    j = nq * 4;
  }
  for (; j < deg; ++j){
    int s = crow[j];
    proc(*(const uint4*)(XL + (size_t)s * 128 + l * 8));
  }

  float r = 1.f / (den + 1e-16f);
  float4 b0 = *(const float4*)(bias + l * 8);
  float4 b1 = *(const float4*)(bias + l * 8 + 4);
  float o[8];
  o[0] = acc[0] * r + b0.x; o[1] = acc[1] * r + b0.y;
  o[2] = acc[2] * r + b0.z; o[3] = acc[3] * r + b0.w;
  o[4] = acc[4] * r + b1.x; o[5] = acc[5] * r + b1.y;
  o[6] = acc[6] * r + b1.z; o[7] = acc[7] * r + b1.w;
  if (MODE == 0){
    #pragma unroll
    for (int c = 0; c < 8; ++c) o[c] = o[c] > 0.f ? o[c] : 0.01f * o[c];
    uint4 pk;
    pk.x = (unsigned int)f2bf(o[0]) | ((unsigned int)f2bf(o[1]) << 16);
    pk.y = (unsigned int)f2bf(o[2]) | ((unsigned int)f2bf(o[3]) << 16);
    pk.z = (unsigned int)f2bf(o[4]) | ((unsigned int)f2bf(o[5]) << 16);
    pk.w = (unsigned int)f2bf(o[6]) | ((unsigned int)f2bf(o[7]) << 16);
    *(uint4*)((unsigned short*)outp + (size_t)gid * 128 + l * 8) = pk;
  } else {
    float4 w0 = *(const float4*)(fcW + l * 8);
    float4 w1 = *(const float4*)(fcW + l * 8 + 4);
    float pv = o[0] * w0.x + o[1] * w0.y + o[2] * w0.z + o[3] * w0.w +
               o[4] * w1.x + o[5] * w1.y + o[6] * w1.z + o[7] * w1.w;
    pv += __shfl_xor(pv, 1, 16);
    pv += __shfl_xor(pv, 2, 16);
    pv += __shfl_xor(pv, 4, 16);
    pv += __shfl_xor(pv, 8, 16);
    if (l == 0) ((float*)outp)[gid] = pv + fcb[0];
  }
}

// ---------------- L3: gather_c1 (first)  U  mark1 ----------------
__global__ __launch_bounds__(256) void k_L3(
    const unsigned short* __restrict__ XLb, const unsigned short* __restrict__ XRb,
    const int* __restrict__ cnt, const int* __restrict__ bucket,
    const float* __restrict__ c1_att, const float* __restrict__ c1_b,
    unsigned short* __restrict__ Hb, int M, int G0,
    int* __restrict__ flag1, int* __restrict__ list1, int* __restrict__ n1, int N){
  int bid = blockIdx.x;
  if (bid < G0){
    int gid = (bid * 256 + (int)threadIdx.x) >> 4;
    int l = threadIdx.x & 15;
    if (gid < M)
      dev_gather16<0>(gid, l, XLb, XRb, cnt, bucket, c1_att, c1_b,
                      nullptr, nullptr, (void*)Hb);
  } else {
    dev_mark1(cnt, bucket, flag1, list1, n1, N);
  }
}

// ---------------- L4: mfma_c2 (first)  U  mark2 ----------------
__global__ __launch_bounds__(256) void k_L4(
    const unsigned short* __restrict__ Hb, const unsigned short* __restrict__ Wt2,
    const float* __restrict__ c2_bl, const float* __restrict__ c2_br,
    unsigned short* __restrict__ XLb, unsigned short* __restrict__ XRb, int nMfma,
    const int* __restrict__ cnt, const int* __restrict__ bucket,
    const int* __restrict__ list1, const int* __restrict__ n1,
    int* __restrict__ flag2, int* __restrict__ list2, int* __restrict__ n2){
  int bid = blockIdx.x;
  if (bid < nMfma){
    dev_gemm_mfma<false>(bid, Hb, Wt2, c2_bl, c2_br, XLb, XRb);
  } else {
    dev_mark2(bid - nMfma, 64, cnt, bucket, list1, n1, flag2, list2, n2);
  }
}

// ---------------- device: dual fp32 GEMM block (512 slots) ----------------
__device__ __forceinline__ void dev_gemm_dual(
    int bid, const float* __restrict__ A,
    const float* __restrict__ Wl, const float* __restrict__ Wr,
    const float* __restrict__ blv, const float* __restrict__ brv,
    float* __restrict__ XL1, float* __restrict__ XR1,
    const int* __restrict__ list1, const int* __restrict__ list2,
    const int* __restrict__ nn,
    float (*As)[17], float (*Ws)[64]){
  const float* W; const float* bias; float* Out; const int* rows; int n;
  int colBase, bx, nbx;
  if (bid < 384){
    W = Wl; bias = blv; Out = XL1; rows = list2; n = nn[1];
    colBase = (bid / 192) * 64; bx = bid % 192; nbx = 192;
  } else {
    int rem = bid - 384;
    W = Wr; bias = brv; Out = XR1; rows = list1; n = nn[0];
    colBase = (rem / 64) * 64; bx = rem % 64; nbx = 64;
  }
  int tid = threadIdx.x;
  int tx = tid & 15, ty = tid >> 4;
  int ar = tid >> 2, ac = (tid & 3) << 2;
  int kr = tid >> 4, nc = (tid & 15) << 2;
  for (int base = bx * 64; base < n; base += nbx * 64){
    float acc[4][4] = {};
    int arow = rows[min(base + ar, n - 1)];
    for (int k0 = 0; k0 < 128; k0 += 16){
      float4 av = *(const float4*)(A + (size_t)arow * 128 + k0 + ac);
      As[ar][ac + 0] = av.x; As[ar][ac + 1] = av.y;
      As[ar][ac + 2] = av.z; As[ar][ac + 3] = av.w;
      float4 wv = *(const float4*)(W + (size_t)(k0 + kr) * 128 + colBase + nc);
      *(float4*)&Ws[kr][nc] = wv;
      __syncthreads();
      #pragma unroll
      for (int kk = 0; kk < 16; ++kk){
        float a0 = As[ty * 4 + 0][kk];
        float a1 = As[ty * 4 + 1][kk];
        float a2 = As[ty * 4 + 2][kk];
        float a3 = As[ty * 4 + 3][kk];
        float4 b = *(const float4*)&Ws[kk][tx * 4];
        acc[0][0] += a0 * b.x; acc[0][1] += a0 * b.y; acc[0][2] += a0 * b.z; acc[0][3] += a0 * b.w;
        acc[1][0] += a1 * b.x; acc[1][1] += a1 * b.y; acc[1][2] += a1 * b.z; acc[1][3] += a1 * b.w;
        acc[2][0] += a2 * b.x; acc[2][1] += a2 * b.y; acc[2][2] += a2 * b.z; acc[2][3] += a2 * b.w;
        acc[3][0] += a3 * b.x; acc[3][1] += a3 * b.y; acc[3][2] += a3 * b.z; acc[3][3] += a3 * b.w;
      }
      __syncthreads();
    }
    int cN = colBase + tx * 4;
    float4 bb = *(const float4*)(bias + cN);
    #pragma unroll
    for (int i = 0; i < 4; ++i){
      int r = rows[min(base + ty * 4 + i, n - 1)];
      float4 o;
      o.x = acc[i][0] + bb.x; o.y = acc[i][1] + bb.y;
      o.z = acc[i][2] + bb.z; o.w = acc[i][3] + bb.w;
      *(float4*)(Out + (size_t)r * 128 + cN) = o;
    }
  }
}

// ---------------- L5: gather_v (first)  U  dual fp32 GEMM ----------------
__global__ __launch_bounds__(256) void k_L5(
    const unsigned short* __restrict__ XLb, const unsigned short* __restrict__ XRb,
    const int* __restrict__ cnt, const int* __restrict__ bucket,
    const float* __restrict__ c2_att, const float* __restrict__ c2_b,
    const float* __restrict__ fcW, const float* __restrict__ fcb,
    float* __restrict__ out_value, int M, int G0,
    const float* __restrict__ x,
    const float* __restrict__ a1_Wl, const float* __restrict__ a1_Wr,
    const float* __restrict__ a1_bl, const float* __restrict__ a1_br,
    float* __restrict__ XL1, float* __restrict__ XR1,
    const int* __restrict__ list1, const int* __restrict__ list2,
    const int* __restrict__ nn){
  int bid = blockIdx.x;
  if (bid < G0){
    int gid = (bid * 256 + (int)threadIdx.x) >> 4;
    int l = threadIdx.x & 15;
    if (gid < M)
      dev_gather16<1>(gid, l, XLb, XRb, cnt, bucket, c2_att, c2_b,
                      fcW, fcb, (void*)out_value);
  } else {
    __shared__ float As[64][17];
    __shared__ float Ws[16][64];
    dev_gemm_dual(bid - G0, x, a1_Wl, a1_Wr, a1_bl, a1_br,
                  XL1, XR1, list1, list2, nn, As, Ws);
  }
}

// ---------------- L6: a1 gather + a2 projections (512 blocks) ----------------
__global__ __launch_bounds__(256) void k_a1_fused(
    const float* __restrict__ XL, const float* __restrict__ XR,
    const int* __restrict__ cnt, const int* __restrict__ bucket,
    const float* __restrict__ att, const float* __restrict__ bias,
    const float* __restrict__ Wl7, const float* __restrict__ Wr7,
    const float* __restrict__ bl7, const float* __restrict__ br7,
    float* __restrict__ XL2, float* __restrict__ XR2,
    const int* __restrict__ list, const int* __restrict__ n_dev){
  int n = *n_dev;
  int lane = threadIdx.x & 63;
  int wstride = (gridDim.x * blockDim.x) >> 6;
  for (int i = ((int)blockIdx.x * 256 + (int)threadIdx.x) >> 6; i < n; i += wstride){
    int wid = list[i];
    float2 xr = ((const float2*)(XR + (size_t)wid * 128))[lane];
    float2 at = ((const float2*)att)[lane];
    int deg = min(cnt[wid], 64);
    const int* crow = bucket + (size_t)wid * 64;
    float m = -INFINITY, den = 0.f, acc0 = 0.f, acc1 = 0.f;
    for (int j = -1; j < deg; ++j){
      int s = (j < 0) ? wid : crow[j];
      float2 xl = ((const float2*)(XL + (size_t)s * 128))[lane];
      float v0 = xl.x + xr.x, v1 = xl.y + xr.y;
      v0 = v0 > 0.f ? v0 : 0.2f * v0;
      v1 = v1 > 0.f ? v1 : 0.2f * v1;
      float e = wave_reduce_sum(v0 * at.x + v1 * at.y);
      float mn = fmaxf(m, e);
      float sc = __expf(m - mn);
      float p  = __expf(e - mn);
      den  = den  * sc + p;
      acc0 = acc0 * sc + p * xl.x;
      acc1 = acc1 * sc + p * xl.y;
      m = mn;
    }
    float r = 1.f / (den + 1e-16f);
    float2 bs = ((const float2*)bias)[lane];
    float o0 = acc0 * r + bs.x;
    float o1 = acc1 * r + bs.y;
    o0 = o0 > 0.f ? o0 : 0.01f * o0;
    o1 = o1 > 0.f ? o1 : 0.01f * o1;
    #pragma unroll
    for (int c = 0; c < 7; ++c){
      float wl0 = Wl7[(size_t)(2 * lane) * 7 + c];
      float wl1 = Wl7[(size_t)(2 * lane + 1) * 7 + c];
      float wr0 = Wr7[(size_t)(2 * lane) * 7 + c];
      float wr1 = Wr7[(size_t)(2 * lane + 1) * 7 + c];
      float dl = wave_reduce_sum(o0 * wl0 + o1 * wl1);
      float dr = wave_reduce_sum(o0 * wr0 + o1 * wr1);
      if (lane == 0){
        XL2[(size_t)wid * 8 + c] = dl + bl7[c];
        XR2[(size_t)wid * 8 + c] = dr + br7[c];
      }
    }
  }
}

// ---------------- L7: a2 head (1 block of 256) ----------------
__global__ __launch_bounds__(256) void k_a2head(
    const float* __restrict__ XL2, const float* __restrict__ XR2,
    const int* __restrict__ cnt, const int* __restrict__ bucket,
    const float* __restrict__ att, const float* __restrict__ bias,
    const float* __restrict__ gu,
    float* __restrict__ out_action, float* __restrict__ out_sel, int N){
  __shared__ float pr[32][8];
  int g = threadIdx.x >> 3, c = threadIdx.x & 7;
  int node = (g >> 3) * N + (g & 7);
  float xr = (c < 7) ? XR2[(size_t)node * 8 + c] : 0.f;
  float at = (c < 7) ? att[c] : 0.f;
  int deg = min(cnt[node], 64);
  const int* crow = bucket + (size_t)node * 64;
  float m = -INFINITY, den = 0.f, acc = 0.f;
  for (int j = -1; j < deg; ++j){
    int s = (j < 0) ? node : crow[j];
    float xl = (c < 7) ? XL2[(size_t)s * 8 + c] : 0.f;
    float v = xl + xr;
    v = fmaxf(v, 0.2f * v);
    float e = v * at;
    e += __shfl_xor(e, 1, 8);
    e += __shfl_xor(e, 2, 8);
    e += __shfl_xor(e, 4, 8);
    if (e > m){
      float sc = __expf(m - e);
      den *= sc; acc *= sc; m = e;
    }
    float p = __expf(e - m);
    den += p;
    acc = fmaf(p, xl, acc);
  }
  float lg = acc / (den + 1e-16f) + ((c < 7) ? bias[c] : 0.f);
  float lgv = (c < 7) ? lg : -INFINITY;
  float mx = lgv;
  mx = fmaxf(mx, __shfl_xor(mx, 1, 8));
  mx = fmaxf(mx, __shfl_xor(mx, 2, 8));
  mx = fmaxf(mx, __shfl_xor(mx, 4, 8));
  float ex = (c < 7) ? expf(lgv - mx) : 0.f;
  float sm = ex;
  sm += __shfl_xor(sm, 1, 8);
  sm += __shfl_xor(sm, 2, 8);
  sm += __shfl_xor(sm, 4, 8);
  pr[g][c] = ex / sm;
  __syncthreads();
  int t = threadIdx.x;
  if (t < 32){
    int b = t >> 3;
    float sc[7];
    #pragma unroll
    for (int cc = 0; cc < 7; ++cc){
      float u = gu[t * 7 + cc];
      float gn = -logf(-logf(u));
      sc[cc] = logf(pr[t][cc]) + gn;
    }
    #pragma unroll
    for (int k = 0; k < 4; ++k){
      float best = -INFINITY; int bi = 0;
      #pragma unroll
      for (int cc = 0; cc < 7; ++cc) if (sc[cc] > best){ best = sc[cc]; bi = cc; }
      sc[bi] = -INFINITY;
      out_action[t * 4 + k] = (float)bi;
      out_sel[t * 4 + k] = pr[b * 8 + bi][k];
    }
  }
}

// ---------------------------------------------------------------------------
extern "C" void kernel_launch(void* const* d_in, const int* in_sizes, int n_in,
                              void* d_out, int out_size, void* d_ws, size_t ws_size,
                              hipStream_t stream){
  const float* x  = (const float*)d_in[0];
  const int*   ei = (const int*)d_in[1];
  const float* gu = (const float*)d_in[2];
  const float* a1_Wl = (const float*)d_in[3],  *a1_bl = (const float*)d_in[4];
  const float* a1_Wr = (const float*)d_in[5],  *a1_br = (const float*)d_in[6];
  const float* a1_att= (const float*)d_in[7],  *a1_b  = (const float*)d_in[8];
  const float* a2_Wl = (const float*)d_in[9],  *a2_bl = (const float*)d_in[10];
  const float* a2_Wr = (const float*)d_in[11], *a2_br = (const float*)d_in[12];
  const float* a2_att= (const float*)d_in[13], *a2_b  = (const float*)d_in[14];
  const float* c1_Wl = (const float*)d_in[15], *c1_bl = (const float*)d_in[16];
  const float* c1_Wr = (const float*)d_in[17], *c1_br = (const float*)d_in[18];
  const float* c1_att= (const float*)d_in[19], *c1_b  = (const float*)d_in[20];
  const float* c2_Wl = (const float*)d_in[21], *c2_bl = (const float*)d_in[22];
  const float* c2_Wr = (const float*)d_in[23], *c2_br = (const float*)d_in[24];
  const float* c2_att= (const float*)d_in[25], *c2_b  = (const float*)d_in[26];
  const float* fc_W  = (const float*)d_in[27], *fc_b  = (const float*)d_in[28];

  const int M = in_sizes[0] / 128;     // 40000
  const int E = in_sizes[1] / 2;       // 640000
  const int B = in_sizes[2] / 56;      // 4
  const int N = M / B;                 // 10000
  const int nw = B * 8;                // 32
  const int T = 256;

  char* ws = (char*)d_ws;
  size_t off = 0;
  auto alloc = [&](size_t bytes) -> void* {
    void* p = ws + off;
    off += (bytes + 255) & ~(size_t)255;
    return p;
  };
  // contiguous zero region: cnt | flag1 | flag2 | nn
  int*   cnt    = (int*)alloc((size_t)(3 * M + 2) * 4);
  int*   flag1  = cnt + M;
  int*   flag2  = flag1 + M;
  int*   nn     = flag2 + M;           // nn[0]=n1, nn[1]=n2
  int*   bucket = (int*)alloc((size_t)M * 64 * 4);
  int*   list1  = (int*)alloc((size_t)M * 4);
  int*   list2  = (int*)alloc((size_t)M * 4);
  float* XL2    = (float*)alloc((size_t)M * 8 * 4);
  float* XR2    = (float*)alloc((size_t)M * 8 * 4);
  unsigned short* Wt1 = (unsigned short*)alloc((size_t)256 * 128 * 2);
  unsigned short* Wt2 = (unsigned short*)alloc((size_t)256 * 128 * 2);
  float* XL1 = (float*)alloc((size_t)M * 128 * 4);
  float* XR1 = (float*)alloc((size_t)M * 128 * 4);
  unsigned short* XLb = (unsigned short*)alloc((size_t)M * 128 * 2);
  unsigned short* XRb = (unsigned short*)alloc((size_t)M * 128 * 2);
  unsigned short* Hb  = (unsigned short*)alloc((size_t)M * 128 * 2);
  (void)ws_size; (void)n_in; (void)out_size;

  float* out_action = (float*)d_out;                 // 128
  float* out_sel    = out_action + (size_t)nw * 4;   // 128
  float* out_value  = out_sel + (size_t)nw * 4;      // 40000

  const int G0 = (M * 16 + T - 1) / T;               // 2500 gather blocks
  const int nMfma = M / 64;                          // 625
  const int nS = (E + T - 1) / T;                    // 2500 scatter blocks
  const int nz = 3 * M + 2;

  // L1: zero U weight prep
  k_init<<<(nz + 65536 + T - 1) / T, T, 0, stream>>>(cnt, nz,
      c1_Wl, c1_Wr, c2_Wl, c2_Wr, Wt1, Wt2);
  // L2: scatter U mfma_c1
  k_L2<<<nS + nMfma, T, 0, stream>>>(ei, E, nS, cnt, bucket,
      x, Wt1, c1_bl, c1_br, XLb, XRb);
  // L3: gather_c1 U mark1
  k_L3<<<G0 + 1, T, 0, stream>>>(XLb, XRb, cnt, bucket, c1_att, c1_b,
      Hb, M, G0, flag1, list1, &nn[0], N);
  // L4: mfma_c2 U mark2
  k_L4<<<nMfma + 64, T, 0, stream>>>(Hb, Wt2, c2_bl, c2_br, XLb, XRb, nMfma,
      cnt, bucket, list1, &nn[0], flag2, list2, &nn[1]);
  // L5: gather_v U dual fp32 GEMM
  k_L5<<<G0 + 512, T, 0, stream>>>(XLb, XRb, cnt, bucket, c2_att, c2_b,
      fc_W, fc_b, out_value, M, G0,
      x, a1_Wl, a1_Wr, a1_bl, a1_br, XL1, XR1, list1, list2, nn);
  // L6: a1_fused
  k_a1_fused<<<512, T, 0, stream>>>(XL1, XR1, cnt, bucket, a1_att, a1_b,
      a2_Wl, a2_Wr, a2_bl, a2_br, XL2, XR2, list1, &nn[0]);
  // L7: a2 head
  k_a2head<<<1, 256, 0, stream>>>(XL2, XR2, cnt, bucket, a2_att, a2_b, gu,
      out_action, out_sel, N);
}

// Round 14
// 219.873 us; speedup vs baseline: 1.1407x; 1.1407x over previous
//
#include <hip/hip_runtime.h>
#include <math.h>

// ---------------------------------------------------------------------------
// MyTopoAgent R14 (R12 structure restored; R13's scatter U mfma fusion reverted):
//  L1 init (zero cnt|flags|nn  U  bf16 wt prep)
//  L2 scatter (pure, 2 edges/thread)
//  L3 mfma_c1 U mark1 | L4 mark2 U gather_c1 | L5 dual-fp32 U mfma_c2
//  L6 a1_fused U gather_v | L7 a2head.       7 launches.
// ---------------------------------------------------------------------------

typedef __attribute__((ext_vector_type(8))) short bf16x8;
typedef __attribute__((ext_vector_type(4))) float f32x4;

__device__ __forceinline__ float wave_reduce_sum(float v){
  #pragma unroll
  for (int o = 32; o > 0; o >>= 1) v += __shfl_xor(v, o);
  return v;
}
__device__ __forceinline__ unsigned short f2bf(float f){
  unsigned int u = __float_as_uint(f);
  u += 0x7FFFu + ((u >> 16) & 1u);
  return (unsigned short)(u >> 16);
}
__device__ __forceinline__ void unpack2(unsigned int u, float& a, float& b){
  a = __uint_as_float(u << 16);
  b = __uint_as_float(u & 0xffff0000u);
}

// ---------------- L1: zero cnt|flag1|flag2|nn U bf16 weight prep ----------------
__global__ void k_init(int* __restrict__ p, int nz,
                       const float* __restrict__ W1l, const float* __restrict__ W1r,
                       const float* __restrict__ W2l, const float* __restrict__ W2r,
                       unsigned short* __restrict__ Wt1, unsigned short* __restrict__ Wt2){
  int i = blockIdx.x * blockDim.x + threadIdx.x;
  if (i < nz){
    p[i] = 0;
  } else {
    int r = i - nz;
    if (r < 65536){
      int which = r >> 15;
      int lin = r & 32767;
      const float* Wl = which ? W2l : W1l;
      const float* Wr = which ? W2r : W1r;
      unsigned short* Wt = which ? Wt2 : Wt1;
      int n = lin >> 7, k = lin & 127;
      float v = (n < 128) ? Wl[(size_t)k * 128 + n] : Wr[(size_t)k * 128 + (n - 128)];
      Wt[lin] = f2bf(v);
    }
  }
}

// ---------------- L2: scatter (pure, 2 edges/thread) ----------------
__global__ void k_scatter(const int* __restrict__ ei, int E,
                          int* __restrict__ cnt, int* __restrict__ bucket){
  int t2 = blockIdx.x * blockDim.x + threadIdx.x;
  int e0 = t2 * 2;
  #pragma unroll
  for (int q = 0; q < 2; ++q){
    int e = e0 + q;
    if (e < E){
      int s = ei[e], t = ei[E + e];
      int pos = atomicAdd(&cnt[t], 1);
      if (pos < 64) bucket[(size_t)t * 64 + pos] = s;
    }
  }
}

// ---------------- device: frontier marks ----------------
__device__ __forceinline__ void dev_mark1(
    const int* __restrict__ cnt, const int* __restrict__ bucket,
    int* __restrict__ flag1, int* __restrict__ list1, int* __restrict__ n1, int N){
  int p = threadIdx.x;
  if (p >= 32) return;
  int node = (p >> 3) * N + (p & 7);
  if (atomicExch(&flag1[node], 1) == 0) list1[atomicAdd(n1, 1)] = node;  // self
  int deg = min(cnt[node], 64);
  const int* crow = bucket + (size_t)node * 64;
  for (int j = 0; j < deg; ++j){
    int s = crow[j];
    if (atomicExch(&flag1[s], 1) == 0) list1[atomicAdd(n1, 1)] = s;
  }
}
__device__ __forceinline__ void dev_mark2(
    int vbid, int nblk,
    const int* __restrict__ cnt, const int* __restrict__ bucket,
    const int* __restrict__ list1, const int* __restrict__ n1,
    int* __restrict__ flag2, int* __restrict__ list2, int* __restrict__ n2){
  int n = *n1;
  for (int i = vbid * blockDim.x + threadIdx.x; i < n; i += nblk * blockDim.x){
    int node = list1[i];
    if (atomicExch(&flag2[node], 1) == 0) list2[atomicAdd(n2, 1)] = node;  // self
    int deg = min(cnt[node], 64);
    const int* crow = bucket + (size_t)node * 64;
    for (int j = 0; j < deg; ++j){
      int s = crow[j];
      if (atomicExch(&flag2[s], 1) == 0) list2[atomicAdd(n2, 1)] = s;
    }
  }
}

// ---------------- device: dual fp32 GEMM block (512 slots) ----------------
__device__ __forceinline__ void dev_gemm_dual(
    int bid, const float* __restrict__ A,
    const float* __restrict__ Wl, const float* __restrict__ Wr,
    const float* __restrict__ blv, const float* __restrict__ brv,
    float* __restrict__ XL1, float* __restrict__ XR1,
    const int* __restrict__ list1, const int* __restrict__ list2,
    const int* __restrict__ nn,
    float (*As)[17], float (*Ws)[64]){
  const float* W; const float* bias; float* Out; const int* rows; int n;
  int colBase, bx, nbx;
  if (bid < 384){
    W = Wl; bias = blv; Out = XL1; rows = list2; n = nn[1];
    colBase = (bid / 192) * 64; bx = bid % 192; nbx = 192;
  } else {
    int rem = bid - 384;
    W = Wr; bias = brv; Out = XR1; rows = list1; n = nn[0];
    colBase = (rem / 64) * 64; bx = rem % 64; nbx = 64;
  }
  int tid = threadIdx.x;
  int tx = tid & 15, ty = tid >> 4;
  int ar = tid >> 2, ac = (tid & 3) << 2;
  int kr = tid >> 4, nc = (tid & 15) << 2;
  for (int base = bx * 64; base < n; base += nbx * 64){
    float acc[4][4] = {};
    int arow = rows[min(base + ar, n - 1)];
    for (int k0 = 0; k0 < 128; k0 += 16){
      float4 av = *(const float4*)(A + (size_t)arow * 128 + k0 + ac);
      As[ar][ac + 0] = av.x; As[ar][ac + 1] = av.y;
      As[ar][ac + 2] = av.z; As[ar][ac + 3] = av.w;
      float4 wv = *(const float4*)(W + (size_t)(k0 + kr) * 128 + colBase + nc);
      *(float4*)&Ws[kr][nc] = wv;
      __syncthreads();
      #pragma unroll
      for (int kk = 0; kk < 16; ++kk){
        float a0 = As[ty * 4 + 0][kk];
        float a1 = As[ty * 4 + 1][kk];
        float a2 = As[ty * 4 + 2][kk];
        float a3 = As[ty * 4 + 3][kk];
        float4 b = *(const float4*)&Ws[kk][tx * 4];
        acc[0][0] += a0 * b.x; acc[0][1] += a0 * b.y; acc[0][2] += a0 * b.z; acc[0][3] += a0 * b.w;
        acc[1][0] += a1 * b.x; acc[1][1] += a1 * b.y; acc[1][2] += a1 * b.z; acc[1][3] += a1 * b.w;
        acc[2][0] += a2 * b.x; acc[2][1] += a2 * b.y; acc[2][2] += a2 * b.z; acc[2][3] += a2 * b.w;
        acc[3][0] += a3 * b.x; acc[3][1] += a3 * b.y; acc[3][2] += a3 * b.z; acc[3][3] += a3 * b.w;
      }
      __syncthreads();
    }
    int cN = colBase + tx * 4;
    float4 bb = *(const float4*)(bias + cN);
    #pragma unroll
    for (int i = 0; i < 4; ++i){
      int r = rows[min(base + ty * 4 + i, n - 1)];
      float4 o;
      o.x = acc[i][0] + bb.x; o.y = acc[i][1] + bb.y;
      o.z = acc[i][2] + bb.z; o.w = acc[i][3] + bb.w;
      *(float4*)(Out + (size_t)r * 128 + cN) = o;
    }
  }
}

// ---------------- device: MFMA bf16 GEMM block (swapped ops) ----------------
template<bool CVT>
__device__ __forceinline__ void dev_gemm_mfma(
    int rblk, const void* __restrict__ Av, const unsigned short* __restrict__ Wt,
    const float* __restrict__ bl, const float* __restrict__ br,
    unsigned short* __restrict__ XL, unsigned short* __restrict__ XR){
  int w = threadIdx.x >> 6, lane = threadIdx.x & 63;
  int l16 = lane & 15, kg = lane >> 4;
  int rBase = rblk * 64 + w * 16;
  f32x4 acc[16];
  #pragma unroll
  for (int i = 0; i < 16; ++i) acc[i] = (f32x4){0.f, 0.f, 0.f, 0.f};
  #pragma unroll
  for (int ks = 0; ks < 4; ++ks){
    bf16x8 a;
    if constexpr (CVT){
      const float* A = (const float*)Av;
      const float* ap = A + (size_t)(rBase + l16) * 128 + ks * 32 + kg * 8;
      float4 f0 = *(const float4*)ap;
      float4 f1 = *(const float4*)(ap + 4);
      union { bf16x8 v; unsigned short s[8]; } u;
      u.s[0] = f2bf(f0.x); u.s[1] = f2bf(f0.y); u.s[2] = f2bf(f0.z); u.s[3] = f2bf(f0.w);
      u.s[4] = f2bf(f1.x); u.s[5] = f2bf(f1.y); u.s[6] = f2bf(f1.z); u.s[7] = f2bf(f1.w);
      a = u.v;
    } else {
      a = *(const bf16x8*)((const unsigned short*)Av + (size_t)(rBase + l16) * 128 + ks * 32 + kg * 8);
    }
    #pragma unroll
    for (int ct = 0; ct < 16; ++ct){
      bf16x8 wv = *(const bf16x8*)(Wt + (size_t)(ct * 16 + l16) * 128 + ks * 32 + kg * 8);
      acc[ct] = __builtin_amdgcn_mfma_f32_16x16x32_bf16(wv, a, acc[ct], 0, 0, 0);
    }
  }
  int row = rBase + l16;
  #pragma unroll
  for (int ct = 0; ct < 16; ++ct){
    int col = ct * 16 + kg * 4;
    const float* bp = (col < 128) ? (bl + col) : (br + (col - 128));
    float4 bb = *(const float4*)bp;
    unsigned int p0 = (unsigned int)f2bf(acc[ct][0] + bb.x) |
                      ((unsigned int)f2bf(acc[ct][1] + bb.y) << 16);
    unsigned int p1 = (unsigned int)f2bf(acc[ct][2] + bb.z) |
                      ((unsigned int)f2bf(acc[ct][3] + bb.w) << 16);
    unsigned short* dst = (col < 128) ? (XL + (size_t)row * 128 + col)
                                      : (XR + (size_t)row * 128 + (col - 128));
    uint2 pk; pk.x = p0; pk.y = p1;
    *(uint2*)dst = pk;
  }
}

// ---------------- device: bf16 gather (implicit self, quad depth-1) ----------------
template<int MODE>
__device__ __forceinline__ void dev_gather16(
    int gid, int l,
    const unsigned short* __restrict__ XL, const unsigned short* __restrict__ XR,
    const int* __restrict__ cnt, const int* __restrict__ bucket,
    const float* __restrict__ att, const float* __restrict__ bias,
    const float* __restrict__ fcW, const float* __restrict__ fcb,
    void* __restrict__ outp){
  uint4 xu = *(const uint4*)(XR + (size_t)gid * 128 + l * 8);
  float xr[8];
  unpack2(xu.x, xr[0], xr[1]); unpack2(xu.y, xr[2], xr[3]);
  unpack2(xu.z, xr[4], xr[5]); unpack2(xu.w, xr[6], xr[7]);
  float at[8];
  {
    float4 a0 = *(const float4*)(att + l * 8);
    float4 a1 = *(const float4*)(att + l * 8 + 4);
    at[0] = a0.x; at[1] = a0.y; at[2] = a0.z; at[3] = a0.w;
    at[4] = a1.x; at[5] = a1.y; at[6] = a1.z; at[7] = a1.w;
  }
  int deg = min(cnt[gid], 64);
  const int* __restrict__ crow = bucket + (size_t)gid * 64;
  float m = -INFINITY, den = 0.f;
  float acc[8] = {0.f, 0.f, 0.f, 0.f, 0.f, 0.f, 0.f, 0.f};

  auto proc = [&](uint4 u){
    float xl[8];
    unpack2(u.x, xl[0], xl[1]); unpack2(u.y, xl[2], xl[3]);
    unpack2(u.z, xl[4], xl[5]); unpack2(u.w, xl[6], xl[7]);
    float e = 0.f;
    #pragma unroll
    for (int c = 0; c < 8; ++c){
      float v = xl[c] + xr[c];
      v = fmaxf(v, 0.2f * v);
      e = fmaf(v, at[c], e);
    }
    e += __shfl_xor(e, 1, 16);
    e += __shfl_xor(e, 2, 16);
    e += __shfl_xor(e, 4, 16);
    e += __shfl_xor(e, 8, 16);
    if (e > m){
      float sc = __expf(m - e);
      den *= sc;
      #pragma unroll
      for (int c = 0; c < 8; ++c) acc[c] *= sc;
      m = e;
    }
    float p = __expf(e - m);
    den += p;
    #pragma unroll
    for (int c = 0; c < 8; ++c) acc[c] = fmaf(p, xl[c], acc[c]);
  };

  // self edge
  proc(*(const uint4*)(XL + (size_t)gid * 128 + l * 8));

  // depth-1 quad rotation over real edges
  int nq = deg >> 2;
  int j = 0;
  if (nq > 0){
    uint4 r0, r1, r2, r3;
    {
      int s0 = crow[0], s1 = crow[1], s2 = crow[2], s3 = crow[3];
      r0 = *(const uint4*)(XL + (size_t)s0 * 128 + l * 8);
      r1 = *(const uint4*)(XL + (size_t)s1 * 128 + l * 8);
      r2 = *(const uint4*)(XL + (size_t)s2 * 128 + l * 8);
      r3 = *(const uint4*)(XL + (size_t)s3 * 128 + l * 8);
    }
    for (int q = 1;; ++q){
      bool more = (q < nq);
      uint4 n0, n1, n2, n3;
      if (more){
        int b4 = q * 4;
        int t0 = crow[b4 + 0], t1 = crow[b4 + 1], t2 = crow[b4 + 2], t3 = crow[b4 + 3];
        n0 = *(const uint4*)(XL + (size_t)t0 * 128 + l * 8);
        n1 = *(const uint4*)(XL + (size_t)t1 * 128 + l * 8);
        n2 = *(const uint4*)(XL + (size_t)t2 * 128 + l * 8);
        n3 = *(const uint4*)(XL + (size_t)t3 * 128 + l * 8);
      }
      proc(r0); proc(r1); proc(r2); proc(r3);
      if (!more) break;
      r0 = n0; r1 = n1; r2 = n2; r3 = n3;
    }
    j = nq * 4;
  }
  for (; j < deg; ++j){
    int s = crow[j];
    proc(*(const uint4*)(XL + (size_t)s * 128 + l * 8));
  }

  float r = 1.f / (den + 1e-16f);
  float4 b0 = *(const float4*)(bias + l * 8);
  float4 b1 = *(const float4*)(bias + l * 8 + 4);
  float o[8];
  o[0] = acc[0] * r + b0.x; o[1] = acc[1] * r + b0.y;
  o[2] = acc[2] * r + b0.z; o[3] = acc[3] * r + b0.w;
  o[4] = acc[4] * r + b1.x; o[5] = acc[5] * r + b1.y;
  o[6] = acc[6] * r + b1.z; o[7] = acc[7] * r + b1.w;
  if (MODE == 0){
    #pragma unroll
    for (int c = 0; c < 8; ++c) o[c] = o[c] > 0.f ? o[c] : 0.01f * o[c];
    uint4 pk;
    pk.x = (unsigned int)f2bf(o[0]) | ((unsigned int)f2bf(o[1]) << 16);
    pk.y = (unsigned int)f2bf(o[2]) | ((unsigned int)f2bf(o[3]) << 16);
    pk.z = (unsigned int)f2bf(o[4]) | ((unsigned int)f2bf(o[5]) << 16);
    pk.w = (unsigned int)f2bf(o[6]) | ((unsigned int)f2bf(o[7]) << 16);
    *(uint4*)((unsigned short*)outp + (size_t)gid * 128 + l * 8) = pk;
  } else {
    float4 w0 = *(const float4*)(fcW + l * 8);
    float4 w1 = *(const float4*)(fcW + l * 8 + 4);
    float pv = o[0] * w0.x + o[1] * w0.y + o[2] * w0.z + o[3] * w0.w +
               o[4] * w1.x + o[5] * w1.y + o[6] * w1.z + o[7] * w1.w;
    pv += __shfl_xor(pv, 1, 16);
    pv += __shfl_xor(pv, 2, 16);
    pv += __shfl_xor(pv, 4, 16);
    pv += __shfl_xor(pv, 8, 16);
    if (l == 0) ((float*)outp)[gid] = pv + fcb[0];
  }
}

// ---------------- device: a1 gather + a2 projections ----------------
__device__ __forceinline__ void dev_a1_fused(
    int vbid,
    const float* __restrict__ XL, const float* __restrict__ XR,
    const int* __restrict__ cnt, const int* __restrict__ bucket,
    const float* __restrict__ att, const float* __restrict__ bias,
    const float* __restrict__ Wl7, const float* __restrict__ Wr7,
    const float* __restrict__ bl7, const float* __restrict__ br7,
    float* __restrict__ XL2, float* __restrict__ XR2,
    const int* __restrict__ list, const int* __restrict__ n_dev){
  int n = *n_dev;
  int lane = threadIdx.x & 63;
  const int wstride = (256 * 256) >> 6;   // 1024 virtual waves
  for (int i = (vbid * 256 + (int)threadIdx.x) >> 6; i < n; i += wstride){
    int wid = list[i];
    float2 xr = ((const float2*)(XR + (size_t)wid * 128))[lane];
    float2 at = ((const float2*)att)[lane];
    int deg = min(cnt[wid], 64);
    const int* crow = bucket + (size_t)wid * 64;
    float m = -INFINITY, den = 0.f, acc0 = 0.f, acc1 = 0.f;
    for (int j = -1; j < deg; ++j){
      int s = (j < 0) ? wid : crow[j];
      float2 xl = ((const float2*)(XL + (size_t)s * 128))[lane];
      float v0 = xl.x + xr.x, v1 = xl.y + xr.y;
      v0 = v0 > 0.f ? v0 : 0.2f * v0;
      v1 = v1 > 0.f ? v1 : 0.2f * v1;
      float e = wave_reduce_sum(v0 * at.x + v1 * at.y);
      float mn = fmaxf(m, e);
      float sc = __expf(m - mn);
      float p  = __expf(e - mn);
      den  = den  * sc + p;
      acc0 = acc0 * sc + p * xl.x;
      acc1 = acc1 * sc + p * xl.y;
      m = mn;
    }
    float r = 1.f / (den + 1e-16f);
    float2 bs = ((const float2*)bias)[lane];
    float o0 = acc0 * r + bs.x;
    float o1 = acc1 * r + bs.y;
    o0 = o0 > 0.f ? o0 : 0.01f * o0;
    o1 = o1 > 0.f ? o1 : 0.01f * o1;
    #pragma unroll
    for (int c = 0; c < 7; ++c){
      float wl0 = Wl7[(size_t)(2 * lane) * 7 + c];
      float wl1 = Wl7[(size_t)(2 * lane + 1) * 7 + c];
      float wr0 = Wr7[(size_t)(2 * lane) * 7 + c];
      float wr1 = Wr7[(size_t)(2 * lane + 1) * 7 + c];
      float dl = wave_reduce_sum(o0 * wl0 + o1 * wl1);
      float dr = wave_reduce_sum(o0 * wr0 + o1 * wr1);
      if (lane == 0){
        XL2[(size_t)wid * 8 + c] = dl + bl7[c];
        XR2[(size_t)wid * 8 + c] = dr + br7[c];
      }
    }
  }
}

// ---------------- L3: mfma_c1 U mark1 ----------------
__global__ __launch_bounds__(256) void k_L3(
    const float* __restrict__ x, const unsigned short* __restrict__ Wt1,
    const float* __restrict__ c1_bl, const float* __restrict__ c1_br,
    unsigned short* __restrict__ XLb, unsigned short* __restrict__ XRb, int nMfma,
    const int* __restrict__ cnt, const int* __restrict__ bucket,
    int* __restrict__ flag1, int* __restrict__ list1, int* __restrict__ n1, int N){
  int bid = blockIdx.x;
  if (bid < nMfma){
    dev_gemm_mfma<true>(bid, x, Wt1, c1_bl, c1_br, XLb, XRb);
  } else {
    dev_mark1(cnt, bucket, flag1, list1, n1, N);
  }
}

// ---------------- L4: mark2 (first 64) U gather_c1 ----------------
__global__ __launch_bounds__(256) void k_L4(
    const int* __restrict__ cnt, const int* __restrict__ bucket,
    const int* __restrict__ list1, const int* __restrict__ n1,
    int* __restrict__ flag2, int* __restrict__ list2, int* __restrict__ n2,
    const unsigned short* __restrict__ XLb, const unsigned short* __restrict__ XRb,
    const float* __restrict__ c1_att, const float* __restrict__ c1_b,
    unsigned short* __restrict__ Hb, int M){
  int bid = blockIdx.x;
  if (bid < 64){
    dev_mark2(bid, 64, cnt, bucket, list1, n1, flag2, list2, n2);
  } else {
    int gbid = bid - 64;
    int gid = (gbid * 256 + (int)threadIdx.x) >> 4;
    int l = threadIdx.x & 15;
    if (gid < M)
      dev_gather16<0>(gid, l, XLb, XRb, cnt, bucket, c1_att, c1_b,
                      nullptr, nullptr, (void*)Hb);
  }
}

// ---------------- L5: dual fp32 GEMM (512) U mfma_c2 ----------------
__global__ __launch_bounds__(256) void k_L5(
    const float* __restrict__ x,
    const float* __restrict__ a1_Wl, const float* __restrict__ a1_Wr,
    const float* __restrict__ a1_bl, const float* __restrict__ a1_br,
    float* __restrict__ XL1, float* __restrict__ XR1,
    const int* __restrict__ list1, const int* __restrict__ list2,
    const int* __restrict__ nn,
    const unsigned short* __restrict__ Hb, const unsigned short* __restrict__ Wt2,
    const float* __restrict__ c2_bl, const float* __restrict__ c2_br,
    unsigned short* __restrict__ XLb, unsigned short* __restrict__ XRb){
  __shared__ float As[64][17];
  __shared__ float Ws[16][64];
  int bid = blockIdx.x;
  if (bid < 512){
    dev_gemm_dual(bid, x, a1_Wl, a1_Wr, a1_bl, a1_br, XL1, XR1, list1, list2, nn, As, Ws);
  } else {
    dev_gemm_mfma<false>(bid - 512, Hb, Wt2, c2_bl, c2_br, XLb, XRb);
  }
}

// ---------------- L6: a1_fused (first 256) U gather_v ----------------
__global__ __launch_bounds__(256) void k_L6(
    const float* __restrict__ XL1, const float* __restrict__ XR1,
    const int* __restrict__ cnt, const int* __restrict__ bucket,
    const float* __restrict__ a1_att, const float* __restrict__ a1_b,
    const float* __restrict__ Wl7, const float* __restrict__ Wr7,
    const float* __restrict__ bl7, const float* __restrict__ br7,
    float* __restrict__ XL2, float* __restrict__ XR2,
    const int* __restrict__ list1, const int* __restrict__ n1,
    const unsigned short* __restrict__ XLb, const unsigned short* __restrict__ XRb,
    const float* __restrict__ c2_att, const float* __restrict__ c2_b,
    const float* __restrict__ fcW, const float* __restrict__ fcb,
    float* __restrict__ out_value, int M){
  int bid = blockIdx.x;
  if (bid < 256){
    dev_a1_fused(bid, XL1, XR1, cnt, bucket, a1_att, a1_b,
                 Wl7, Wr7, bl7, br7, XL2, XR2, list1, n1);
  } else {
    int gbid = bid - 256;
    int gid = (gbid * 256 + (int)threadIdx.x) >> 4;
    int l = threadIdx.x & 15;
    if (gid < M)
      dev_gather16<1>(gid, l, XLb, XRb, cnt, bucket, c2_att, c2_b,
                      fcW, fcb, (void*)out_value);
  }
}

// ---------------- L7: a2 head (1 block of 256) ----------------
__global__ __launch_bounds__(256) void k_a2head(
    const float* __restrict__ XL2, const float* __restrict__ XR2,
    const int* __restrict__ cnt, const int* __restrict__ bucket,
    const float* __restrict__ att, const float* __restrict__ bias,
    const float* __restrict__ gu,
    float* __restrict__ out_action, float* __restrict__ out_sel, int N){
  __shared__ float pr[32][8];
  int g = threadIdx.x >> 3, c = threadIdx.x & 7;
  int node = (g >> 3) * N + (g & 7);
  float xr = (c < 7) ? XR2[(size_t)node * 8 + c] : 0.f;
  float at = (c < 7) ? att[c] : 0.f;
  int deg = min(cnt[node], 64);
  const int* crow = bucket + (size_t)node * 64;
  float m = -INFINITY, den = 0.f, acc = 0.f;
  for (int j = -1; j < deg; ++j){
    int s = (j < 0) ? node : crow[j];
    float xl = (c < 7) ? XL2[(size_t)s * 8 + c] : 0.f;
    float v = xl + xr;
    v = fmaxf(v, 0.2f * v);
    float e = v * at;
    e += __shfl_xor(e, 1, 8);
    e += __shfl_xor(e, 2, 8);
    e += __shfl_xor(e, 4, 8);
    if (e > m){
      float sc = __expf(m - e);
      den *= sc; acc *= sc; m = e;
    }
    float p = __expf(e - m);
    den += p;
    acc = fmaf(p, xl, acc);
  }
  float lg = acc / (den + 1e-16f) + ((c < 7) ? bias[c] : 0.f);
  float lgv = (c < 7) ? lg : -INFINITY;
  float mx = lgv;
  mx = fmaxf(mx, __shfl_xor(mx, 1, 8));
  mx = fmaxf(mx, __shfl_xor(mx, 2, 8));
  mx = fmaxf(mx, __shfl_xor(mx, 4, 8));
  float ex = (c < 7) ? expf(lgv - mx) : 0.f;
  float sm = ex;
  sm += __shfl_xor(sm, 1, 8);
  sm += __shfl_xor(sm, 2, 8);
  sm += __shfl_xor(sm, 4, 8);
  pr[g][c] = ex / sm;
  __syncthreads();
  int t = threadIdx.x;
  if (t < 32){
    int b = t >> 3;
    float sc[7];
    #pragma unroll
    for (int cc = 0; cc < 7; ++cc){
      float u = gu[t * 7 + cc];
      float gn = -logf(-logf(u));
      sc[cc] = logf(pr[t][cc]) + gn;
    }
    #pragma unroll
    for (int k = 0; k < 4; ++k){
      float best = -INFINITY; int bi = 0;
      #pragma unroll
      for (int cc = 0; cc < 7; ++cc) if (sc[cc] > best){ best = sc[cc]; bi = cc; }
      sc[bi] = -INFINITY;
      out_action[t * 4 + k] = (float)bi;
      out_sel[t * 4 + k] = pr[b * 8 + bi][k];
    }
  }
}

// ---------------------------------------------------------------------------
extern "C" void kernel_launch(void* const* d_in, const int* in_sizes, int n_in,
                              void* d_out, int out_size, void* d_ws, size_t ws_size,
                              hipStream_t stream){
  const float* x  = (const float*)d_in[0];
  const int*   ei = (const int*)d_in[1];
  const float* gu = (const float*)d_in[2];
  const float* a1_Wl = (const float*)d_in[3],  *a1_bl = (const float*)d_in[4];
  const float* a1_Wr = (const float*)d_in[5],  *a1_br = (const float*)d_in[6];
  const float* a1_att= (const float*)d_in[7],  *a1_b  = (const float*)d_in[8];
  const float* a2_Wl = (const float*)d_in[9],  *a2_bl = (const float*)d_in[10];
  const float* a2_Wr = (const float*)d_in[11], *a2_br = (const float*)d_in[12];
  const float* a2_att= (const float*)d_in[13], *a2_b  = (const float*)d_in[14];
  const float* c1_Wl = (const float*)d_in[15], *c1_bl = (const float*)d_in[16];
  const float* c1_Wr = (const float*)d_in[17], *c1_br = (const float*)d_in[18];
  const float* c1_att= (const float*)d_in[19], *c1_b  = (const float*)d_in[20];
  const float* c2_Wl = (const float*)d_in[21], *c2_bl = (const float*)d_in[22];
  const float* c2_Wr = (const float*)d_in[23], *c2_br = (const float*)d_in[24];
  const float* c2_att= (const float*)d_in[25], *c2_b  = (const float*)d_in[26];
  const float* fc_W  = (const float*)d_in[27], *fc_b  = (const float*)d_in[28];

  const int M = in_sizes[0] / 128;     // 40000
  const int E = in_sizes[1] / 2;       // 640000
  const int B = in_sizes[2] / 56;      // 4
  const int N = M / B;                 // 10000
  const int nw = B * 8;                // 32
  const int T = 256;

  char* ws = (char*)d_ws;
  size_t off = 0;
  auto alloc = [&](size_t bytes) -> void* {
    void* p = ws + off;
    off += (bytes + 255) & ~(size_t)255;
    return p;
  };
  // contiguous zero region: cnt | flag1 | flag2 | nn
  int*   cnt    = (int*)alloc((size_t)(3 * M + 2) * 4);
  int*   flag1  = cnt + M;
  int*   flag2  = flag1 + M;
  int*   nn     = flag2 + M;           // nn[0]=n1, nn[1]=n2
  int*   bucket = (int*)alloc((size_t)M * 64 * 4);
  int*   list1  = (int*)alloc((size_t)M * 4);
  int*   list2  = (int*)alloc((size_t)M * 4);
  float* XL2    = (float*)alloc((size_t)M * 8 * 4);
  float* XR2    = (float*)alloc((size_t)M * 8 * 4);
  unsigned short* Wt1 = (unsigned short*)alloc((size_t)256 * 128 * 2);
  unsigned short* Wt2 = (unsigned short*)alloc((size_t)256 * 128 * 2);
  float* XL1 = (float*)alloc((size_t)M * 128 * 4);
  float* XR1 = (float*)alloc((size_t)M * 128 * 4);
  unsigned short* XLb = (unsigned short*)alloc((size_t)M * 128 * 2);
  unsigned short* XRb = (unsigned short*)alloc((size_t)M * 128 * 2);
  unsigned short* Hb  = (unsigned short*)alloc((size_t)M * 128 * 2);
  (void)ws_size; (void)n_in; (void)out_size;

  float* out_action = (float*)d_out;                 // 128
  float* out_sel    = out_action + (size_t)nw * 4;   // 128
  float* out_value  = out_sel + (size_t)nw * 4;      // 40000

  const int G0 = (M * 16 + T - 1) / T;               // 2500 gather blocks
  const int nMfma = M / 64;                          // 625
  const int nz = 3 * M + 2;

  // L1: zero U weight prep
  k_init<<<(nz + 65536 + T - 1) / T, T, 0, stream>>>(cnt, nz,
      c1_Wl, c1_Wr, c2_Wl, c2_Wr, Wt1, Wt2);
  // L2: scatter (pure, 2 edges/thread)
  k_scatter<<<((E + 1) / 2 + T - 1) / T, T, 0, stream>>>(ei, E, cnt, bucket);
  // L3: mfma_c1 U mark1
  k_L3<<<nMfma + 1, T, 0, stream>>>(x, Wt1, c1_bl, c1_br, XLb, XRb, nMfma,
      cnt, bucket, flag1, list1, &nn[0], N);
  // L4: mark2 U gather_c1
  k_L4<<<64 + G0, T, 0, stream>>>(cnt, bucket, list1, &nn[0], flag2, list2, &nn[1],
      XLb, XRb, c1_att, c1_b, Hb, M);
  // L5: dual fp32 GEMM U mfma_c2
  k_L5<<<512 + nMfma, T, 0, stream>>>(x, a1_Wl, a1_Wr, a1_bl, a1_br,
      XL1, XR1, list1, list2, nn, Hb, Wt2, c2_bl, c2_br, XLb, XRb);
  // L6: a1_fused U gather_v
  k_L6<<<256 + G0, T, 0, stream>>>(XL1, XR1, cnt, bucket, a1_att, a1_b,
      a2_Wl, a2_Wr, a2_bl, a2_br, XL2, XR2, list1, &nn[0],
      XLb, XRb, c2_att, c2_b, fc_W, fc_b, out_value, M);
  // L7: a2 head
  k_a2head<<<1, 256, 0, stream>>>(XL2, XR2, cnt, bucket, a2_att, a2_b, gu,
      out_action, out_sel, N);
}

// Round 15
// 207.569 us; speedup vs baseline: 1.2083x; 1.0593x over previous
//
#include <hip/hip_runtime.h>
#include <math.h>

// ---------------------------------------------------------------------------
// MyTopoAgent R15 (R12 structure + L1 wt-prep; scatter reverted to 1 edge/thr):
//  L1 init (zero cnt|flags|nn U bf16 wt prep)
//  L2 scatter (pure, 1 edge/thread, max waves)
//  L3 mfma_c1 U mark1 | L4 mark2 U gather_c1 | L5 dual-fp32 U mfma_c2
//  L6 a1_fused U gather_v | L7 a2head.       7 launches.
// ---------------------------------------------------------------------------

typedef __attribute__((ext_vector_type(8))) short bf16x8;
typedef __attribute__((ext_vector_type(4))) float f32x4;

__device__ __forceinline__ float wave_reduce_sum(float v){
  #pragma unroll
  for (int o = 32; o > 0; o >>= 1) v += __shfl_xor(v, o);
  return v;
}
__device__ __forceinline__ unsigned short f2bf(float f){
  unsigned int u = __float_as_uint(f);
  u += 0x7FFFu + ((u >> 16) & 1u);
  return (unsigned short)(u >> 16);
}
__device__ __forceinline__ void unpack2(unsigned int u, float& a, float& b){
  a = __uint_as_float(u << 16);
  b = __uint_as_float(u & 0xffff0000u);
}

// ---------------- L1: zero cnt|flag1|flag2|nn U bf16 weight prep ----------------
__global__ void k_init(int* __restrict__ p, int nz,
                       const float* __restrict__ W1l, const float* __restrict__ W1r,
                       const float* __restrict__ W2l, const float* __restrict__ W2r,
                       unsigned short* __restrict__ Wt1, unsigned short* __restrict__ Wt2){
  int i = blockIdx.x * blockDim.x + threadIdx.x;
  if (i < nz){
    p[i] = 0;
  } else {
    int r = i - nz;
    if (r < 65536){
      int which = r >> 15;
      int lin = r & 32767;
      const float* Wl = which ? W2l : W1l;
      const float* Wr = which ? W2r : W1r;
      unsigned short* Wt = which ? Wt2 : Wt1;
      int n = lin >> 7, k = lin & 127;
      float v = (n < 128) ? Wl[(size_t)k * 128 + n] : Wr[(size_t)k * 128 + (n - 128)];
      Wt[lin] = f2bf(v);
    }
  }
}

// ---------------- L2: scatter (pure, 1 edge/thread) ----------------
__global__ void k_scatter(const int* __restrict__ ei, int E,
                          int* __restrict__ cnt, int* __restrict__ bucket){
  int e = blockIdx.x * blockDim.x + threadIdx.x;
  if (e >= E) return;
  int s = ei[e], t = ei[E + e];
  int pos = atomicAdd(&cnt[t], 1);
  if (pos < 64) bucket[(size_t)t * 64 + pos] = s;
}

// ---------------- device: frontier marks ----------------
__device__ __forceinline__ void dev_mark1(
    const int* __restrict__ cnt, const int* __restrict__ bucket,
    int* __restrict__ flag1, int* __restrict__ list1, int* __restrict__ n1, int N){
  int p = threadIdx.x;
  if (p >= 32) return;
  int node = (p >> 3) * N + (p & 7);
  if (atomicExch(&flag1[node], 1) == 0) list1[atomicAdd(n1, 1)] = node;  // self
  int deg = min(cnt[node], 64);
  const int* crow = bucket + (size_t)node * 64;
  for (int j = 0; j < deg; ++j){
    int s = crow[j];
    if (atomicExch(&flag1[s], 1) == 0) list1[atomicAdd(n1, 1)] = s;
  }
}
__device__ __forceinline__ void dev_mark2(
    int vbid, int nblk,
    const int* __restrict__ cnt, const int* __restrict__ bucket,
    const int* __restrict__ list1, const int* __restrict__ n1,
    int* __restrict__ flag2, int* __restrict__ list2, int* __restrict__ n2){
  int n = *n1;
  for (int i = vbid * blockDim.x + threadIdx.x; i < n; i += nblk * blockDim.x){
    int node = list1[i];
    if (atomicExch(&flag2[node], 1) == 0) list2[atomicAdd(n2, 1)] = node;  // self
    int deg = min(cnt[node], 64);
    const int* crow = bucket + (size_t)node * 64;
    for (int j = 0; j < deg; ++j){
      int s = crow[j];
      if (atomicExch(&flag2[s], 1) == 0) list2[atomicAdd(n2, 1)] = s;
    }
  }
}

// ---------------- device: dual fp32 GEMM block (512 slots) ----------------
__device__ __forceinline__ void dev_gemm_dual(
    int bid, const float* __restrict__ A,
    const float* __restrict__ Wl, const float* __restrict__ Wr,
    const float* __restrict__ blv, const float* __restrict__ brv,
    float* __restrict__ XL1, float* __restrict__ XR1,
    const int* __restrict__ list1, const int* __restrict__ list2,
    const int* __restrict__ nn,
    float (*As)[17], float (*Ws)[64]){
  const float* W; const float* bias; float* Out; const int* rows; int n;
  int colBase, bx, nbx;
  if (bid < 384){
    W = Wl; bias = blv; Out = XL1; rows = list2; n = nn[1];
    colBase = (bid / 192) * 64; bx = bid % 192; nbx = 192;
  } else {
    int rem = bid - 384;
    W = Wr; bias = brv; Out = XR1; rows = list1; n = nn[0];
    colBase = (rem / 64) * 64; bx = rem % 64; nbx = 64;
  }
  int tid = threadIdx.x;
  int tx = tid & 15, ty = tid >> 4;
  int ar = tid >> 2, ac = (tid & 3) << 2;
  int kr = tid >> 4, nc = (tid & 15) << 2;
  for (int base = bx * 64; base < n; base += nbx * 64){
    float acc[4][4] = {};
    int arow = rows[min(base + ar, n - 1)];
    for (int k0 = 0; k0 < 128; k0 += 16){
      float4 av = *(const float4*)(A + (size_t)arow * 128 + k0 + ac);
      As[ar][ac + 0] = av.x; As[ar][ac + 1] = av.y;
      As[ar][ac + 2] = av.z; As[ar][ac + 3] = av.w;
      float4 wv = *(const float4*)(W + (size_t)(k0 + kr) * 128 + colBase + nc);
      *(float4*)&Ws[kr][nc] = wv;
      __syncthreads();
      #pragma unroll
      for (int kk = 0; kk < 16; ++kk){
        float a0 = As[ty * 4 + 0][kk];
        float a1 = As[ty * 4 + 1][kk];
        float a2 = As[ty * 4 + 2][kk];
        float a3 = As[ty * 4 + 3][kk];
        float4 b = *(const float4*)&Ws[kk][tx * 4];
        acc[0][0] += a0 * b.x; acc[0][1] += a0 * b.y; acc[0][2] += a0 * b.z; acc[0][3] += a0 * b.w;
        acc[1][0] += a1 * b.x; acc[1][1] += a1 * b.y; acc[1][2] += a1 * b.z; acc[1][3] += a1 * b.w;
        acc[2][0] += a2 * b.x; acc[2][1] += a2 * b.y; acc[2][2] += a2 * b.z; acc[2][3] += a2 * b.w;
        acc[3][0] += a3 * b.x; acc[3][1] += a3 * b.y; acc[3][2] += a3 * b.z; acc[3][3] += a3 * b.w;
      }
      __syncthreads();
    }
    int cN = colBase + tx * 4;
    float4 bb = *(const float4*)(bias + cN);
    #pragma unroll
    for (int i = 0; i < 4; ++i){
      int r = rows[min(base + ty * 4 + i, n - 1)];
      float4 o;
      o.x = acc[i][0] + bb.x; o.y = acc[i][1] + bb.y;
      o.z = acc[i][2] + bb.z; o.w = acc[i][3] + bb.w;
      *(float4*)(Out + (size_t)r * 128 + cN) = o;
    }
  }
}

// ---------------- device: MFMA bf16 GEMM block (swapped ops) ----------------
template<bool CVT>
__device__ __forceinline__ void dev_gemm_mfma(
    int rblk, const void* __restrict__ Av, const unsigned short* __restrict__ Wt,
    const float* __restrict__ bl, const float* __restrict__ br,
    unsigned short* __restrict__ XL, unsigned short* __restrict__ XR){
  int w = threadIdx.x >> 6, lane = threadIdx.x & 63;
  int l16 = lane & 15, kg = lane >> 4;
  int rBase = rblk * 64 + w * 16;
  f32x4 acc[16];
  #pragma unroll
  for (int i = 0; i < 16; ++i) acc[i] = (f32x4){0.f, 0.f, 0.f, 0.f};
  #pragma unroll
  for (int ks = 0; ks < 4; ++ks){
    bf16x8 a;
    if constexpr (CVT){
      const float* A = (const float*)Av;
      const float* ap = A + (size_t)(rBase + l16) * 128 + ks * 32 + kg * 8;
      float4 f0 = *(const float4*)ap;
      float4 f1 = *(const float4*)(ap + 4);
      union { bf16x8 v; unsigned short s[8]; } u;
      u.s[0] = f2bf(f0.x); u.s[1] = f2bf(f0.y); u.s[2] = f2bf(f0.z); u.s[3] = f2bf(f0.w);
      u.s[4] = f2bf(f1.x); u.s[5] = f2bf(f1.y); u.s[6] = f2bf(f1.z); u.s[7] = f2bf(f1.w);
      a = u.v;
    } else {
      a = *(const bf16x8*)((const unsigned short*)Av + (size_t)(rBase + l16) * 128 + ks * 32 + kg * 8);
    }
    #pragma unroll
    for (int ct = 0; ct < 16; ++ct){
      bf16x8 wv = *(const bf16x8*)(Wt + (size_t)(ct * 16 + l16) * 128 + ks * 32 + kg * 8);
      acc[ct] = __builtin_amdgcn_mfma_f32_16x16x32_bf16(wv, a, acc[ct], 0, 0, 0);
    }
  }
  int row = rBase + l16;
  #pragma unroll
  for (int ct = 0; ct < 16; ++ct){
    int col = ct * 16 + kg * 4;
    const float* bp = (col < 128) ? (bl + col) : (br + (col - 128));
    float4 bb = *(const float4*)bp;
    unsigned int p0 = (unsigned int)f2bf(acc[ct][0] + bb.x) |
                      ((unsigned int)f2bf(acc[ct][1] + bb.y) << 16);
    unsigned int p1 = (unsigned int)f2bf(acc[ct][2] + bb.z) |
                      ((unsigned int)f2bf(acc[ct][3] + bb.w) << 16);
    unsigned short* dst = (col < 128) ? (XL + (size_t)row * 128 + col)
                                      : (XR + (size_t)row * 128 + (col - 128));
    uint2 pk; pk.x = p0; pk.y = p1;
    *(uint2*)dst = pk;
  }
}

// ---------------- device: bf16 gather (implicit self, quad depth-1) ----------------
template<int MODE>
__device__ __forceinline__ void dev_gather16(
    int gid, int l,
    const unsigned short* __restrict__ XL, const unsigned short* __restrict__ XR,
    const int* __restrict__ cnt, const int* __restrict__ bucket,
    const float* __restrict__ att, const float* __restrict__ bias,
    const float* __restrict__ fcW, const float* __restrict__ fcb,
    void* __restrict__ outp){
  uint4 xu = *(const uint4*)(XR + (size_t)gid * 128 + l * 8);
  float xr[8];
  unpack2(xu.x, xr[0], xr[1]); unpack2(xu.y, xr[2], xr[3]);
  unpack2(xu.z, xr[4], xr[5]); unpack2(xu.w, xr[6], xr[7]);
  float at[8];
  {
    float4 a0 = *(const float4*)(att + l * 8);
    float4 a1 = *(const float4*)(att + l * 8 + 4);
    at[0] = a0.x; at[1] = a0.y; at[2] = a0.z; at[3] = a0.w;
    at[4] = a1.x; at[5] = a1.y; at[6] = a1.z; at[7] = a1.w;
  }
  int deg = min(cnt[gid], 64);
  const int* __restrict__ crow = bucket + (size_t)gid * 64;
  float m = -INFINITY, den = 0.f;
  float acc[8] = {0.f, 0.f, 0.f, 0.f, 0.f, 0.f, 0.f, 0.f};

  auto proc = [&](uint4 u){
    float xl[8];
    unpack2(u.x, xl[0], xl[1]); unpack2(u.y, xl[2], xl[3]);
    unpack2(u.z, xl[4], xl[5]); unpack2(u.w, xl[6], xl[7]);
    float e = 0.f;
    #pragma unroll
    for (int c = 0; c < 8; ++c){
      float v = xl[c] + xr[c];
      v = fmaxf(v, 0.2f * v);
      e = fmaf(v, at[c], e);
    }
    e += __shfl_xor(e, 1, 16);
    e += __shfl_xor(e, 2, 16);
    e += __shfl_xor(e, 4, 16);
    e += __shfl_xor(e, 8, 16);
    if (e > m){
      float sc = __expf(m - e);
      den *= sc;
      #pragma unroll
      for (int c = 0; c < 8; ++c) acc[c] *= sc;
      m = e;
    }
    float p = __expf(e - m);
    den += p;
    #pragma unroll
    for (int c = 0; c < 8; ++c) acc[c] = fmaf(p, xl[c], acc[c]);
  };

  // self edge
  proc(*(const uint4*)(XL + (size_t)gid * 128 + l * 8));

  // depth-1 quad rotation over real edges
  int nq = deg >> 2;
  int j = 0;
  if (nq > 0){
    uint4 r0, r1, r2, r3;
    {
      int s0 = crow[0], s1 = crow[1], s2 = crow[2], s3 = crow[3];
      r0 = *(const uint4*)(XL + (size_t)s0 * 128 + l * 8);
      r1 = *(const uint4*)(XL + (size_t)s1 * 128 + l * 8);
      r2 = *(const uint4*)(XL + (size_t)s2 * 128 + l * 8);
      r3 = *(const uint4*)(XL + (size_t)s3 * 128 + l * 8);
    }
    for (int q = 1;; ++q){
      bool more = (q < nq);
      uint4 n0, n1, n2, n3;
      if (more){
        int b4 = q * 4;
        int t0 = crow[b4 + 0], t1 = crow[b4 + 1], t2 = crow[b4 + 2], t3 = crow[b4 + 3];
        n0 = *(const uint4*)(XL + (size_t)t0 * 128 + l * 8);
        n1 = *(const uint4*)(XL + (size_t)t1 * 128 + l * 8);
        n2 = *(const uint4*)(XL + (size_t)t2 * 128 + l * 8);
        n3 = *(const uint4*)(XL + (size_t)t3 * 128 + l * 8);
      }
      proc(r0); proc(r1); proc(r2); proc(r3);
      if (!more) break;
      r0 = n0; r1 = n1; r2 = n2; r3 = n3;
    }
    j = nq * 4;
  }
  for (; j < deg; ++j){
    int s = crow[j];
    proc(*(const uint4*)(XL + (size_t)s * 128 + l * 8));
  }

  float r = 1.f / (den + 1e-16f);
  float4 b0 = *(const float4*)(bias + l * 8);
  float4 b1 = *(const float4*)(bias + l * 8 + 4);
  float o[8];
  o[0] = acc[0] * r + b0.x; o[1] = acc[1] * r + b0.y;
  o[2] = acc[2] * r + b0.z; o[3] = acc[3] * r + b0.w;
  o[4] = acc[4] * r + b1.x; o[5] = acc[5] * r + b1.y;
  o[6] = acc[6] * r + b1.z; o[7] = acc[7] * r + b1.w;
  if (MODE == 0){
    #pragma unroll
    for (int c = 0; c < 8; ++c) o[c] = o[c] > 0.f ? o[c] : 0.01f * o[c];
    uint4 pk;
    pk.x = (unsigned int)f2bf(o[0]) | ((unsigned int)f2bf(o[1]) << 16);
    pk.y = (unsigned int)f2bf(o[2]) | ((unsigned int)f2bf(o[3]) << 16);
    pk.z = (unsigned int)f2bf(o[4]) | ((unsigned int)f2bf(o[5]) << 16);
    pk.w = (unsigned int)f2bf(o[6]) | ((unsigned int)f2bf(o[7]) << 16);
    *(uint4*)((unsigned short*)outp + (size_t)gid * 128 + l * 8) = pk;
  } else {
    float4 w0 = *(const float4*)(fcW + l * 8);
    float4 w1 = *(const float4*)(fcW + l * 8 + 4);
    float pv = o[0] * w0.x + o[1] * w0.y + o[2] * w0.z + o[3] * w0.w +
               o[4] * w1.x + o[5] * w1.y + o[6] * w1.z + o[7] * w1.w;
    pv += __shfl_xor(pv, 1, 16);
    pv += __shfl_xor(pv, 2, 16);
    pv += __shfl_xor(pv, 4, 16);
    pv += __shfl_xor(pv, 8, 16);
    if (l == 0) ((float*)outp)[gid] = pv + fcb[0];
  }
}

// ---------------- device: a1 gather + a2 projections ----------------
__device__ __forceinline__ void dev_a1_fused(
    int vbid,
    const float* __restrict__ XL, const float* __restrict__ XR,
    const int* __restrict__ cnt, const int* __restrict__ bucket,
    const float* __restrict__ att, const float* __restrict__ bias,
    const float* __restrict__ Wl7, const float* __restrict__ Wr7,
    const float* __restrict__ bl7, const float* __restrict__ br7,
    float* __restrict__ XL2, float* __restrict__ XR2,
    const int* __restrict__ list, const int* __restrict__ n_dev){
  int n = *n_dev;
  int lane = threadIdx.x & 63;
  const int wstride = (256 * 256) >> 6;   // 1024 virtual waves
  for (int i = (vbid * 256 + (int)threadIdx.x) >> 6; i < n; i += wstride){
    int wid = list[i];
    float2 xr = ((const float2*)(XR + (size_t)wid * 128))[lane];
    float2 at = ((const float2*)att)[lane];
    int deg = min(cnt[wid], 64);
    const int* crow = bucket + (size_t)wid * 64;
    float m = -INFINITY, den = 0.f, acc0 = 0.f, acc1 = 0.f;
    for (int j = -1; j < deg; ++j){
      int s = (j < 0) ? wid : crow[j];
      float2 xl = ((const float2*)(XL + (size_t)s * 128))[lane];
      float v0 = xl.x + xr.x, v1 = xl.y + xr.y;
      v0 = v0 > 0.f ? v0 : 0.2f * v0;
      v1 = v1 > 0.f ? v1 : 0.2f * v1;
      float e = wave_reduce_sum(v0 * at.x + v1 * at.y);
      float mn = fmaxf(m, e);
      float sc = __expf(m - mn);
      float p  = __expf(e - mn);
      den  = den  * sc + p;
      acc0 = acc0 * sc + p * xl.x;
      acc1 = acc1 * sc + p * xl.y;
      m = mn;
    }
    float r = 1.f / (den + 1e-16f);
    float2 bs = ((const float2*)bias)[lane];
    float o0 = acc0 * r + bs.x;
    float o1 = acc1 * r + bs.y;
    o0 = o0 > 0.f ? o0 : 0.01f * o0;
    o1 = o1 > 0.f ? o1 : 0.01f * o1;
    #pragma unroll
    for (int c = 0; c < 7; ++c){
      float wl0 = Wl7[(size_t)(2 * lane) * 7 + c];
      float wl1 = Wl7[(size_t)(2 * lane + 1) * 7 + c];
      float wr0 = Wr7[(size_t)(2 * lane) * 7 + c];
      float wr1 = Wr7[(size_t)(2 * lane + 1) * 7 + c];
      float dl = wave_reduce_sum(o0 * wl0 + o1 * wl1);
      float dr = wave_reduce_sum(o0 * wr0 + o1 * wr1);
      if (lane == 0){
        XL2[(size_t)wid * 8 + c] = dl + bl7[c];
        XR2[(size_t)wid * 8 + c] = dr + br7[c];
      }
    }
  }
}

// ---------------- L3: mfma_c1 U mark1 ----------------
__global__ __launch_bounds__(256) void k_L3(
    const float* __restrict__ x, const unsigned short* __restrict__ Wt1,
    const float* __restrict__ c1_bl, const float* __restrict__ c1_br,
    unsigned short* __restrict__ XLb, unsigned short* __restrict__ XRb, int nMfma,
    const int* __restrict__ cnt, const int* __restrict__ bucket,
    int* __restrict__ flag1, int* __restrict__ list1, int* __restrict__ n1, int N){
  int bid = blockIdx.x;
  if (bid < nMfma){
    dev_gemm_mfma<true>(bid, x, Wt1, c1_bl, c1_br, XLb, XRb);
  } else {
    dev_mark1(cnt, bucket, flag1, list1, n1, N);
  }
}

// ---------------- L4: mark2 (first 64) U gather_c1 ----------------
__global__ __launch_bounds__(256) void k_L4(
    const int* __restrict__ cnt, const int* __restrict__ bucket,
    const int* __restrict__ list1, const int* __restrict__ n1,
    int* __restrict__ flag2, int* __restrict__ list2, int* __restrict__ n2,
    const unsigned short* __restrict__ XLb, const unsigned short* __restrict__ XRb,
    const float* __restrict__ c1_att, const float* __restrict__ c1_b,
    unsigned short* __restrict__ Hb, int M){
  int bid = blockIdx.x;
  if (bid < 64){
    dev_mark2(bid, 64, cnt, bucket, list1, n1, flag2, list2, n2);
  } else {
    int gbid = bid - 64;
    int gid = (gbid * 256 + (int)threadIdx.x) >> 4;
    int l = threadIdx.x & 15;
    if (gid < M)
      dev_gather16<0>(gid, l, XLb, XRb, cnt, bucket, c1_att, c1_b,
                      nullptr, nullptr, (void*)Hb);
  }
}

// ---------------- L5: dual fp32 GEMM (512) U mfma_c2 ----------------
__global__ __launch_bounds__(256) void k_L5(
    const float* __restrict__ x,
    const float* __restrict__ a1_Wl, const float* __restrict__ a1_Wr,
    const float* __restrict__ a1_bl, const float* __restrict__ a1_br,
    float* __restrict__ XL1, float* __restrict__ XR1,
    const int* __restrict__ list1, const int* __restrict__ list2,
    const int* __restrict__ nn,
    const unsigned short* __restrict__ Hb, const unsigned short* __restrict__ Wt2,
    const float* __restrict__ c2_bl, const float* __restrict__ c2_br,
    unsigned short* __restrict__ XLb, unsigned short* __restrict__ XRb){
  __shared__ float As[64][17];
  __shared__ float Ws[16][64];
  int bid = blockIdx.x;
  if (bid < 512){
    dev_gemm_dual(bid, x, a1_Wl, a1_Wr, a1_bl, a1_br, XL1, XR1, list1, list2, nn, As, Ws);
  } else {
    dev_gemm_mfma<false>(bid - 512, Hb, Wt2, c2_bl, c2_br, XLb, XRb);
  }
}

// ---------------- L6: a1_fused (first 256) U gather_v ----------------
__global__ __launch_bounds__(256) void k_L6(
    const float* __restrict__ XL1, const float* __restrict__ XR1,
    const int* __restrict__ cnt, const int* __restrict__ bucket,
    const float* __restrict__ a1_att, const float* __restrict__ a1_b,
    const float* __restrict__ Wl7, const float* __restrict__ Wr7,
    const float* __restrict__ bl7, const float* __restrict__ br7,
    float* __restrict__ XL2, float* __restrict__ XR2,
    const int* __restrict__ list1, const int* __restrict__ n1,
    const unsigned short* __restrict__ XLb, const unsigned short* __restrict__ XRb,
    const float* __restrict__ c2_att, const float* __restrict__ c2_b,
    const float* __restrict__ fcW, const float* __restrict__ fcb,
    float* __restrict__ out_value, int M){
  int bid = blockIdx.x;
  if (bid < 256){
    dev_a1_fused(bid, XL1, XR1, cnt, bucket, a1_att, a1_b,
                 Wl7, Wr7, bl7, br7, XL2, XR2, list1, n1);
  } else {
    int gbid = bid - 256;
    int gid = (gbid * 256 + (int)threadIdx.x) >> 4;
    int l = threadIdx.x & 15;
    if (gid < M)
      dev_gather16<1>(gid, l, XLb, XRb, cnt, bucket, c2_att, c2_b,
                      fcW, fcb, (void*)out_value);
  }
}

// ---------------- L7: a2 head (1 block of 256) ----------------
__global__ __launch_bounds__(256) void k_a2head(
    const float* __restrict__ XL2, const float* __restrict__ XR2,
    const int* __restrict__ cnt, const int* __restrict__ bucket,
    const float* __restrict__ att, const float* __restrict__ bias,
    const float* __restrict__ gu,
    float* __restrict__ out_action, float* __restrict__ out_sel, int N){
  __shared__ float pr[32][8];
  int g = threadIdx.x >> 3, c = threadIdx.x & 7;
  int node = (g >> 3) * N + (g & 7);
  float xr = (c < 7) ? XR2[(size_t)node * 8 + c] : 0.f;
  float at = (c < 7) ? att[c] : 0.f;
  int deg = min(cnt[node], 64);
  const int* crow = bucket + (size_t)node * 64;
  float m = -INFINITY, den = 0.f, acc = 0.f;
  for (int j = -1; j < deg; ++j){
    int s = (j < 0) ? node : crow[j];
    float xl = (c < 7) ? XL2[(size_t)s * 8 + c] : 0.f;
    float v = xl + xr;
    v = fmaxf(v, 0.2f * v);
    float e = v * at;
    e += __shfl_xor(e, 1, 8);
    e += __shfl_xor(e, 2, 8);
    e += __shfl_xor(e, 4, 8);
    if (e > m){
      float sc = __expf(m - e);
      den *= sc; acc *= sc; m = e;
    }
    float p = __expf(e - m);
    den += p;
    acc = fmaf(p, xl, acc);
  }
  float lg = acc / (den + 1e-16f) + ((c < 7) ? bias[c] : 0.f);
  float lgv = (c < 7) ? lg : -INFINITY;
  float mx = lgv;
  mx = fmaxf(mx, __shfl_xor(mx, 1, 8));
  mx = fmaxf(mx, __shfl_xor(mx, 2, 8));
  mx = fmaxf(mx, __shfl_xor(mx, 4, 8));
  float ex = (c < 7) ? expf(lgv - mx) : 0.f;
  float sm = ex;
  sm += __shfl_xor(sm, 1, 8);
  sm += __shfl_xor(sm, 2, 8);
  sm += __shfl_xor(sm, 4, 8);
  pr[g][c] = ex / sm;
  __syncthreads();
  int t = threadIdx.x;
  if (t < 32){
    int b = t >> 3;
    float sc[7];
    #pragma unroll
    for (int cc = 0; cc < 7; ++cc){
      float u = gu[t * 7 + cc];
      float gn = -logf(-logf(u));
      sc[cc] = logf(pr[t][cc]) + gn;
    }
    #pragma unroll
    for (int k = 0; k < 4; ++k){
      float best = -INFINITY; int bi = 0;
      #pragma unroll
      for (int cc = 0; cc < 7; ++cc) if (sc[cc] > best){ best = sc[cc]; bi = cc; }
      sc[bi] = -INFINITY;
      out_action[t * 4 + k] = (float)bi;
      out_sel[t * 4 + k] = pr[b * 8 + bi][k];
    }
  }
}

// ---------------------------------------------------------------------------
extern "C" void kernel_launch(void* const* d_in, const int* in_sizes, int n_in,
                              void* d_out, int out_size, void* d_ws, size_t ws_size,
                              hipStream_t stream){
  const float* x  = (const float*)d_in[0];
  const int*   ei = (const int*)d_in[1];
  const float* gu = (const float*)d_in[2];
  const float* a1_Wl = (const float*)d_in[3],  *a1_bl = (const float*)d_in[4];
  const float* a1_Wr = (const float*)d_in[5],  *a1_br = (const float*)d_in[6];
  const float* a1_att= (const float*)d_in[7],  *a1_b  = (const float*)d_in[8];
  const float* a2_Wl = (const float*)d_in[9],  *a2_bl = (const float*)d_in[10];
  const float* a2_Wr = (const float*)d_in[11], *a2_br = (const float*)d_in[12];
  const float* a2_att= (const float*)d_in[13], *a2_b  = (const float*)d_in[14];
  const float* c1_Wl = (const float*)d_in[15], *c1_bl = (const float*)d_in[16];
  const float* c1_Wr = (const float*)d_in[17], *c1_br = (const float*)d_in[18];
  const float* c1_att= (const float*)d_in[19], *c1_b  = (const float*)d_in[20];
  const float* c2_Wl = (const float*)d_in[21], *c2_bl = (const float*)d_in[22];
  const float* c2_Wr = (const float*)d_in[23], *c2_br = (const float*)d_in[24];
  const float* c2_att= (const float*)d_in[25], *c2_b  = (const float*)d_in[26];
  const float* fc_W  = (const float*)d_in[27], *fc_b  = (const float*)d_in[28];

  const int M = in_sizes[0] / 128;     // 40000
  const int E = in_sizes[1] / 2;       // 640000
  const int B = in_sizes[2] / 56;      // 4
  const int N = M / B;                 // 10000
  const int nw = B * 8;                // 32
  const int T = 256;

  char* ws = (char*)d_ws;
  size_t off = 0;
  auto alloc = [&](size_t bytes) -> void* {
    void* p = ws + off;
    off += (bytes + 255) & ~(size_t)255;
    return p;
  };
  // contiguous zero region: cnt | flag1 | flag2 | nn
  int*   cnt    = (int*)alloc((size_t)(3 * M + 2) * 4);
  int*   flag1  = cnt + M;
  int*   flag2  = flag1 + M;
  int*   nn     = flag2 + M;           // nn[0]=n1, nn[1]=n2
  int*   bucket = (int*)alloc((size_t)M * 64 * 4);
  int*   list1  = (int*)alloc((size_t)M * 4);
  int*   list2  = (int*)alloc((size_t)M * 4);
  float* XL2    = (float*)alloc((size_t)M * 8 * 4);
  float* XR2    = (float*)alloc((size_t)M * 8 * 4);
  unsigned short* Wt1 = (unsigned short*)alloc((size_t)256 * 128 * 2);
  unsigned short* Wt2 = (unsigned short*)alloc((size_t)256 * 128 * 2);
  float* XL1 = (float*)alloc((size_t)M * 128 * 4);
  float* XR1 = (float*)alloc((size_t)M * 128 * 4);
  unsigned short* XLb = (unsigned short*)alloc((size_t)M * 128 * 2);
  unsigned short* XRb = (unsigned short*)alloc((size_t)M * 128 * 2);
  unsigned short* Hb  = (unsigned short*)alloc((size_t)M * 128 * 2);
  (void)ws_size; (void)n_in; (void)out_size;

  float* out_action = (float*)d_out;                 // 128
  float* out_sel    = out_action + (size_t)nw * 4;   // 128
  float* out_value  = out_sel + (size_t)nw * 4;      // 40000

  const int G0 = (M * 16 + T - 1) / T;               // 2500 gather blocks
  const int nMfma = M / 64;                          // 625
  const int nz = 3 * M + 2;

  // L1: zero U weight prep
  k_init<<<(nz + 65536 + T - 1) / T, T, 0, stream>>>(cnt, nz,
      c1_Wl, c1_Wr, c2_Wl, c2_Wr, Wt1, Wt2);
  // L2: scatter (pure, 1 edge/thread)
  k_scatter<<<(E + T - 1) / T, T, 0, stream>>>(ei, E, cnt, bucket);
  // L3: mfma_c1 U mark1
  k_L3<<<nMfma + 1, T, 0, stream>>>(x, Wt1, c1_bl, c1_br, XLb, XRb, nMfma,
      cnt, bucket, flag1, list1, &nn[0], N);
  // L4: mark2 U gather_c1
  k_L4<<<64 + G0, T, 0, stream>>>(cnt, bucket, list1, &nn[0], flag2, list2, &nn[1],
      XLb, XRb, c1_att, c1_b, Hb, M);
  // L5: dual fp32 GEMM U mfma_c2
  k_L5<<<512 + nMfma, T, 0, stream>>>(x, a1_Wl, a1_Wr, a1_bl, a1_br,
      XL1, XR1, list1, list2, nn, Hb, Wt2, c2_bl, c2_br, XLb, XRb);
  // L6: a1_fused U gather_v
  k_L6<<<256 + G0, T, 0, stream>>>(XL1, XR1, cnt, bucket, a1_att, a1_b,
      a2_Wl, a2_Wr, a2_bl, a2_br, XL2, XR2, list1, &nn[0],
      XLb, XRb, c2_att, c2_b, fc_W, fc_b, out_value, M);
  // L7: a2 head
  k_a2head<<<1, 256, 0, stream>>>(XL2, XR2, cnt, bucket, a2_att, a2_b, gu,
      out_action, out_sel, N);
}

// Round 16
// 206.180 us; speedup vs baseline: 1.2165x; 1.0067x over previous
//
#include <hip/hip_runtime.h>
#include <math.h>

// ---------------------------------------------------------------------------
// MyTopoAgent R16 (R15 + ushort bucket + a2head folded into L6 last-block):
//  L1 init (zero cnt|flags|nn|done U bf16 wt prep)
//  L2 scatter (1 edge/thread, ushort bucket)
//  L3 mfma_c1 U mark1 | L4 mark2 U gather_c1 | L5 dual-fp32 U mfma_c2
//  L6 a1_fused U gather_v U (last-block) a2head.     6 launches.
// ---------------------------------------------------------------------------

typedef __attribute__((ext_vector_type(8))) short bf16x8;
typedef __attribute__((ext_vector_type(4))) float f32x4;

__device__ __forceinline__ float wave_reduce_sum(float v){
  #pragma unroll
  for (int o = 32; o > 0; o >>= 1) v += __shfl_xor(v, o);
  return v;
}
__device__ __forceinline__ unsigned short f2bf(float f){
  unsigned int u = __float_as_uint(f);
  u += 0x7FFFu + ((u >> 16) & 1u);
  return (unsigned short)(u >> 16);
}
__device__ __forceinline__ void unpack2(unsigned int u, float& a, float& b){
  a = __uint_as_float(u << 16);
  b = __uint_as_float(u & 0xffff0000u);
}

// ---------------- L1: zero cnt|flag1|flag2|nn|done U bf16 weight prep ----------------
__global__ void k_init(int* __restrict__ p, int nz,
                       const float* __restrict__ W1l, const float* __restrict__ W1r,
                       const float* __restrict__ W2l, const float* __restrict__ W2r,
                       unsigned short* __restrict__ Wt1, unsigned short* __restrict__ Wt2){
  int i = blockIdx.x * blockDim.x + threadIdx.x;
  if (i < nz){
    p[i] = 0;
  } else {
    int r = i - nz;
    if (r < 65536){
      int which = r >> 15;
      int lin = r & 32767;
      const float* Wl = which ? W2l : W1l;
      const float* Wr = which ? W2r : W1r;
      unsigned short* Wt = which ? Wt2 : Wt1;
      int n = lin >> 7, k = lin & 127;
      float v = (n < 128) ? Wl[(size_t)k * 128 + n] : Wr[(size_t)k * 128 + (n - 128)];
      Wt[lin] = f2bf(v);
    }
  }
}

// ---------------- L2: scatter (1 edge/thread, ushort bucket) ----------------
__global__ void k_scatter(const int* __restrict__ ei, int E,
                          int* __restrict__ cnt, unsigned short* __restrict__ bucket){
  int e = blockIdx.x * blockDim.x + threadIdx.x;
  if (e >= E) return;
  int s = ei[e], t = ei[E + e];
  int pos = atomicAdd(&cnt[t], 1);
  if (pos < 64) bucket[(size_t)t * 64 + pos] = (unsigned short)s;
}

// ---------------- device: frontier marks ----------------
__device__ __forceinline__ void dev_mark1(
    const int* __restrict__ cnt, const unsigned short* __restrict__ bucket,
    int* __restrict__ flag1, int* __restrict__ list1, int* __restrict__ n1, int N){
  int p = threadIdx.x;
  if (p >= 32) return;
  int node = (p >> 3) * N + (p & 7);
  if (atomicExch(&flag1[node], 1) == 0) list1[atomicAdd(n1, 1)] = node;  // self
  int deg = min(cnt[node], 64);
  const unsigned short* crow = bucket + (size_t)node * 64;
  for (int j = 0; j < deg; ++j){
    int s = crow[j];
    if (atomicExch(&flag1[s], 1) == 0) list1[atomicAdd(n1, 1)] = s;
  }
}
__device__ __forceinline__ void dev_mark2(
    int vbid, int nblk,
    const int* __restrict__ cnt, const unsigned short* __restrict__ bucket,
    const int* __restrict__ list1, const int* __restrict__ n1,
    int* __restrict__ flag2, int* __restrict__ list2, int* __restrict__ n2){
  int n = *n1;
  for (int i = vbid * blockDim.x + threadIdx.x; i < n; i += nblk * blockDim.x){
    int node = list1[i];
    if (atomicExch(&flag2[node], 1) == 0) list2[atomicAdd(n2, 1)] = node;  // self
    int deg = min(cnt[node], 64);
    const unsigned short* crow = bucket + (size_t)node * 64;
    for (int j = 0; j < deg; ++j){
      int s = crow[j];
      if (atomicExch(&flag2[s], 1) == 0) list2[atomicAdd(n2, 1)] = s;
    }
  }
}

// ---------------- device: dual fp32 GEMM block (512 slots) ----------------
__device__ __forceinline__ void dev_gemm_dual(
    int bid, const float* __restrict__ A,
    const float* __restrict__ Wl, const float* __restrict__ Wr,
    const float* __restrict__ blv, const float* __restrict__ brv,
    float* __restrict__ XL1, float* __restrict__ XR1,
    const int* __restrict__ list1, const int* __restrict__ list2,
    const int* __restrict__ nn,
    float (*As)[17], float (*Ws)[64]){
  const float* W; const float* bias; float* Out; const int* rows; int n;
  int colBase, bx, nbx;
  if (bid < 384){
    W = Wl; bias = blv; Out = XL1; rows = list2; n = nn[1];
    colBase = (bid / 192) * 64; bx = bid % 192; nbx = 192;
  } else {
    int rem = bid - 384;
    W = Wr; bias = brv; Out = XR1; rows = list1; n = nn[0];
    colBase = (rem / 64) * 64; bx = rem % 64; nbx = 64;
  }
  int tid = threadIdx.x;
  int tx = tid & 15, ty = tid >> 4;
  int ar = tid >> 2, ac = (tid & 3) << 2;
  int kr = tid >> 4, nc = (tid & 15) << 2;
  for (int base = bx * 64; base < n; base += nbx * 64){
    float acc[4][4] = {};
    int arow = rows[min(base + ar, n - 1)];
    for (int k0 = 0; k0 < 128; k0 += 16){
      float4 av = *(const float4*)(A + (size_t)arow * 128 + k0 + ac);
      As[ar][ac + 0] = av.x; As[ar][ac + 1] = av.y;
      As[ar][ac + 2] = av.z; As[ar][ac + 3] = av.w;
      float4 wv = *(const float4*)(W + (size_t)(k0 + kr) * 128 + colBase + nc);
      *(float4*)&Ws[kr][nc] = wv;
      __syncthreads();
      #pragma unroll
      for (int kk = 0; kk < 16; ++kk){
        float a0 = As[ty * 4 + 0][kk];
        float a1 = As[ty * 4 + 1][kk];
        float a2 = As[ty * 4 + 2][kk];
        float a3 = As[ty * 4 + 3][kk];
        float4 b = *(const float4*)&Ws[kk][tx * 4];
        acc[0][0] += a0 * b.x; acc[0][1] += a0 * b.y; acc[0][2] += a0 * b.z; acc[0][3] += a0 * b.w;
        acc[1][0] += a1 * b.x; acc[1][1] += a1 * b.y; acc[1][2] += a1 * b.z; acc[1][3] += a1 * b.w;
        acc[2][0] += a2 * b.x; acc[2][1] += a2 * b.y; acc[2][2] += a2 * b.z; acc[2][3] += a2 * b.w;
        acc[3][0] += a3 * b.x; acc[3][1] += a3 * b.y; acc[3][2] += a3 * b.z; acc[3][3] += a3 * b.w;
      }
      __syncthreads();
    }
    int cN = colBase + tx * 4;
    float4 bb = *(const float4*)(bias + cN);
    #pragma unroll
    for (int i = 0; i < 4; ++i){
      int r = rows[min(base + ty * 4 + i, n - 1)];
      float4 o;
      o.x = acc[i][0] + bb.x; o.y = acc[i][1] + bb.y;
      o.z = acc[i][2] + bb.z; o.w = acc[i][3] + bb.w;
      *(float4*)(Out + (size_t)r * 128 + cN) = o;
    }
  }
}

// ---------------- device: MFMA bf16 GEMM block (swapped ops) ----------------
template<bool CVT>
__device__ __forceinline__ void dev_gemm_mfma(
    int rblk, const void* __restrict__ Av, const unsigned short* __restrict__ Wt,
    const float* __restrict__ bl, const float* __restrict__ br,
    unsigned short* __restrict__ XL, unsigned short* __restrict__ XR){
  int w = threadIdx.x >> 6, lane = threadIdx.x & 63;
  int l16 = lane & 15, kg = lane >> 4;
  int rBase = rblk * 64 + w * 16;
  f32x4 acc[16];
  #pragma unroll
  for (int i = 0; i < 16; ++i) acc[i] = (f32x4){0.f, 0.f, 0.f, 0.f};
  #pragma unroll
  for (int ks = 0; ks < 4; ++ks){
    bf16x8 a;
    if constexpr (CVT){
      const float* A = (const float*)Av;
      const float* ap = A + (size_t)(rBase + l16) * 128 + ks * 32 + kg * 8;
      float4 f0 = *(const float4*)ap;
      float4 f1 = *(const float4*)(ap + 4);
      union { bf16x8 v; unsigned short s[8]; } u;
      u.s[0] = f2bf(f0.x); u.s[1] = f2bf(f0.y); u.s[2] = f2bf(f0.z); u.s[3] = f2bf(f0.w);
      u.s[4] = f2bf(f1.x); u.s[5] = f2bf(f1.y); u.s[6] = f2bf(f1.z); u.s[7] = f2bf(f1.w);
      a = u.v;
    } else {
      a = *(const bf16x8*)((const unsigned short*)Av + (size_t)(rBase + l16) * 128 + ks * 32 + kg * 8);
    }
    #pragma unroll
    for (int ct = 0; ct < 16; ++ct){
      bf16x8 wv = *(const bf16x8*)(Wt + (size_t)(ct * 16 + l16) * 128 + ks * 32 + kg * 8);
      acc[ct] = __builtin_amdgcn_mfma_f32_16x16x32_bf16(wv, a, acc[ct], 0, 0, 0);
    }
  }
  int row = rBase + l16;
  #pragma unroll
  for (int ct = 0; ct < 16; ++ct){
    int col = ct * 16 + kg * 4;
    const float* bp = (col < 128) ? (bl + col) : (br + (col - 128));
    float4 bb = *(const float4*)bp;
    unsigned int p0 = (unsigned int)f2bf(acc[ct][0] + bb.x) |
                      ((unsigned int)f2bf(acc[ct][1] + bb.y) << 16);
    unsigned int p1 = (unsigned int)f2bf(acc[ct][2] + bb.z) |
                      ((unsigned int)f2bf(acc[ct][3] + bb.w) << 16);
    unsigned short* dst = (col < 128) ? (XL + (size_t)row * 128 + col)
                                      : (XR + (size_t)row * 128 + (col - 128));
    uint2 pk; pk.x = p0; pk.y = p1;
    *(uint2*)dst = pk;
  }
}

// ---------------- device: bf16 gather (implicit self, quad depth-1) ----------------
template<int MODE>
__device__ __forceinline__ void dev_gather16(
    int gid, int l,
    const unsigned short* __restrict__ XL, const unsigned short* __restrict__ XR,
    const int* __restrict__ cnt, const unsigned short* __restrict__ bucket,
    const float* __restrict__ att, const float* __restrict__ bias,
    const float* __restrict__ fcW, const float* __restrict__ fcb,
    void* __restrict__ outp){
  uint4 xu = *(const uint4*)(XR + (size_t)gid * 128 + l * 8);
  float xr[8];
  unpack2(xu.x, xr[0], xr[1]); unpack2(xu.y, xr[2], xr[3]);
  unpack2(xu.z, xr[4], xr[5]); unpack2(xu.w, xr[6], xr[7]);
  float at[8];
  {
    float4 a0 = *(const float4*)(att + l * 8);
    float4 a1 = *(const float4*)(att + l * 8 + 4);
    at[0] = a0.x; at[1] = a0.y; at[2] = a0.z; at[3] = a0.w;
    at[4] = a1.x; at[5] = a1.y; at[6] = a1.z; at[7] = a1.w;
  }
  int deg = min(cnt[gid], 64);
  const unsigned short* __restrict__ crow = bucket + (size_t)gid * 64;
  float m = -INFINITY, den = 0.f;
  float acc[8] = {0.f, 0.f, 0.f, 0.f, 0.f, 0.f, 0.f, 0.f};

  auto proc = [&](uint4 u){
    float xl[8];
    unpack2(u.x, xl[0], xl[1]); unpack2(u.y, xl[2], xl[3]);
    unpack2(u.z, xl[4], xl[5]); unpack2(u.w, xl[6], xl[7]);
    float e = 0.f;
    #pragma unroll
    for (int c = 0; c < 8; ++c){
      float v = xl[c] + xr[c];
      v = fmaxf(v, 0.2f * v);
      e = fmaf(v, at[c], e);
    }
    e += __shfl_xor(e, 1, 16);
    e += __shfl_xor(e, 2, 16);
    e += __shfl_xor(e, 4, 16);
    e += __shfl_xor(e, 8, 16);
    if (e > m){
      float sc = __expf(m - e);
      den *= sc;
      #pragma unroll
      for (int c = 0; c < 8; ++c) acc[c] *= sc;
      m = e;
    }
    float p = __expf(e - m);
    den += p;
    #pragma unroll
    for (int c = 0; c < 8; ++c) acc[c] = fmaf(p, xl[c], acc[c]);
  };

  // self edge
  proc(*(const uint4*)(XL + (size_t)gid * 128 + l * 8));

  // depth-1 quad rotation over real edges
  int nq = deg >> 2;
  int j = 0;
  if (nq > 0){
    uint4 r0, r1, r2, r3;
    {
      int s0 = crow[0], s1 = crow[1], s2 = crow[2], s3 = crow[3];
      r0 = *(const uint4*)(XL + (size_t)s0 * 128 + l * 8);
      r1 = *(const uint4*)(XL + (size_t)s1 * 128 + l * 8);
      r2 = *(const uint4*)(XL + (size_t)s2 * 128 + l * 8);
      r3 = *(const uint4*)(XL + (size_t)s3 * 128 + l * 8);
    }
    for (int q = 1;; ++q){
      bool more = (q < nq);
      uint4 n0, n1, n2, n3;
      if (more){
        int b4 = q * 4;
        int t0 = crow[b4 + 0], t1 = crow[b4 + 1], t2 = crow[b4 + 2], t3 = crow[b4 + 3];
        n0 = *(const uint4*)(XL + (size_t)t0 * 128 + l * 8);
        n1 = *(const uint4*)(XL + (size_t)t1 * 128 + l * 8);
        n2 = *(const uint4*)(XL + (size_t)t2 * 128 + l * 8);
        n3 = *(const uint4*)(XL + (size_t)t3 * 128 + l * 8);
      }
      proc(r0); proc(r1); proc(r2); proc(r3);
      if (!more) break;
      r0 = n0; r1 = n1; r2 = n2; r3 = n3;
    }
    j = nq * 4;
  }
  for (; j < deg; ++j){
    int s = crow[j];
    proc(*(const uint4*)(XL + (size_t)s * 128 + l * 8));
  }

  float r = 1.f / (den + 1e-16f);
  float4 b0 = *(const float4*)(bias + l * 8);
  float4 b1 = *(const float4*)(bias + l * 8 + 4);
  float o[8];
  o[0] = acc[0] * r + b0.x; o[1] = acc[1] * r + b0.y;
  o[2] = acc[2] * r + b0.z; o[3] = acc[3] * r + b0.w;
  o[4] = acc[4] * r + b1.x; o[5] = acc[5] * r + b1.y;
  o[6] = acc[6] * r + b1.z; o[7] = acc[7] * r + b1.w;
  if (MODE == 0){
    #pragma unroll
    for (int c = 0; c < 8; ++c) o[c] = o[c] > 0.f ? o[c] : 0.01f * o[c];
    uint4 pk;
    pk.x = (unsigned int)f2bf(o[0]) | ((unsigned int)f2bf(o[1]) << 16);
    pk.y = (unsigned int)f2bf(o[2]) | ((unsigned int)f2bf(o[3]) << 16);
    pk.z = (unsigned int)f2bf(o[4]) | ((unsigned int)f2bf(o[5]) << 16);
    pk.w = (unsigned int)f2bf(o[6]) | ((unsigned int)f2bf(o[7]) << 16);
    *(uint4*)((unsigned short*)outp + (size_t)gid * 128 + l * 8) = pk;
  } else {
    float4 w0 = *(const float4*)(fcW + l * 8);
    float4 w1 = *(const float4*)(fcW + l * 8 + 4);
    float pv = o[0] * w0.x + o[1] * w0.y + o[2] * w0.z + o[3] * w0.w +
               o[4] * w1.x + o[5] * w1.y + o[6] * w1.z + o[7] * w1.w;
    pv += __shfl_xor(pv, 1, 16);
    pv += __shfl_xor(pv, 2, 16);
    pv += __shfl_xor(pv, 4, 16);
    pv += __shfl_xor(pv, 8, 16);
    if (l == 0) ((float*)outp)[gid] = pv + fcb[0];
  }
}

// ---------------- device: a1 gather + a2 projections ----------------
__device__ __forceinline__ void dev_a1_fused(
    int vbid,
    const float* __restrict__ XL, const float* __restrict__ XR,
    const int* __restrict__ cnt, const unsigned short* __restrict__ bucket,
    const float* __restrict__ att, const float* __restrict__ bias,
    const float* __restrict__ Wl7, const float* __restrict__ Wr7,
    const float* __restrict__ bl7, const float* __restrict__ br7,
    float* __restrict__ XL2, float* __restrict__ XR2,
    const int* __restrict__ list, const int* __restrict__ n_dev){
  int n = *n_dev;
  int lane = threadIdx.x & 63;
  const int wstride = (256 * 256) >> 6;   // 1024 virtual waves
  for (int i = (vbid * 256 + (int)threadIdx.x) >> 6; i < n; i += wstride){
    int wid = list[i];
    float2 xr = ((const float2*)(XR + (size_t)wid * 128))[lane];
    float2 at = ((const float2*)att)[lane];
    int deg = min(cnt[wid], 64);
    const unsigned short* crow = bucket + (size_t)wid * 64;
    float m = -INFINITY, den = 0.f, acc0 = 0.f, acc1 = 0.f;
    for (int j = -1; j < deg; ++j){
      int s = (j < 0) ? wid : crow[j];
      float2 xl = ((const float2*)(XL + (size_t)s * 128))[lane];
      float v0 = xl.x + xr.x, v1 = xl.y + xr.y;
      v0 = v0 > 0.f ? v0 : 0.2f * v0;
      v1 = v1 > 0.f ? v1 : 0.2f * v1;
      float e = wave_reduce_sum(v0 * at.x + v1 * at.y);
      float mn = fmaxf(m, e);
      float sc = __expf(m - mn);
      float p  = __expf(e - mn);
      den  = den  * sc + p;
      acc0 = acc0 * sc + p * xl.x;
      acc1 = acc1 * sc + p * xl.y;
      m = mn;
    }
    float r = 1.f / (den + 1e-16f);
    float2 bs = ((const float2*)bias)[lane];
    float o0 = acc0 * r + bs.x;
    float o1 = acc1 * r + bs.y;
    o0 = o0 > 0.f ? o0 : 0.01f * o0;
    o1 = o1 > 0.f ? o1 : 0.01f * o1;
    #pragma unroll
    for (int c = 0; c < 7; ++c){
      float wl0 = Wl7[(size_t)(2 * lane) * 7 + c];
      float wl1 = Wl7[(size_t)(2 * lane + 1) * 7 + c];
      float wr0 = Wr7[(size_t)(2 * lane) * 7 + c];
      float wr1 = Wr7[(size_t)(2 * lane + 1) * 7 + c];
      float dl = wave_reduce_sum(o0 * wl0 + o1 * wl1);
      float dr = wave_reduce_sum(o0 * wr0 + o1 * wr1);
      if (lane == 0){
        XL2[(size_t)wid * 8 + c] = dl + bl7[c];
        XR2[(size_t)wid * 8 + c] = dr + br7[c];
      }
    }
  }
}

// ---------------- device: a2 head (one block of 256) ----------------
__device__ __forceinline__ void dev_a2head(
    float (*pr)[8],
    const float* __restrict__ XL2, const float* __restrict__ XR2,
    const int* __restrict__ cnt, const unsigned short* __restrict__ bucket,
    const float* __restrict__ att, const float* __restrict__ bias,
    const float* __restrict__ gu,
    float* __restrict__ out_action, float* __restrict__ out_sel, int N){
  int g = threadIdx.x >> 3, c = threadIdx.x & 7;
  int node = (g >> 3) * N + (g & 7);
  float xr = (c < 7) ? XR2[(size_t)node * 8 + c] : 0.f;
  float at = (c < 7) ? att[c] : 0.f;
  int deg = min(cnt[node], 64);
  const unsigned short* crow = bucket + (size_t)node * 64;
  float m = -INFINITY, den = 0.f, acc = 0.f;
  for (int j = -1; j < deg; ++j){
    int s = (j < 0) ? node : crow[j];
    float xl = (c < 7) ? XL2[(size_t)s * 8 + c] : 0.f;
    float v = xl + xr;
    v = fmaxf(v, 0.2f * v);
    float e = v * at;
    e += __shfl_xor(e, 1, 8);
    e += __shfl_xor(e, 2, 8);
    e += __shfl_xor(e, 4, 8);
    if (e > m){
      float sc = __expf(m - e);
      den *= sc; acc *= sc; m = e;
    }
    float p = __expf(e - m);
    den += p;
    acc = fmaf(p, xl, acc);
  }
  float lg = acc / (den + 1e-16f) + ((c < 7) ? bias[c] : 0.f);
  float lgv = (c < 7) ? lg : -INFINITY;
  float mx = lgv;
  mx = fmaxf(mx, __shfl_xor(mx, 1, 8));
  mx = fmaxf(mx, __shfl_xor(mx, 2, 8));
  mx = fmaxf(mx, __shfl_xor(mx, 4, 8));
  float ex = (c < 7) ? expf(lgv - mx) : 0.f;
  float sm = ex;
  sm += __shfl_xor(sm, 1, 8);
  sm += __shfl_xor(sm, 2, 8);
  sm += __shfl_xor(sm, 4, 8);
  pr[g][c] = ex / sm;
  __syncthreads();
  int t = threadIdx.x;
  if (t < 32){
    int b = t >> 3;
    float sc[7];
    #pragma unroll
    for (int cc = 0; cc < 7; ++cc){
      float u = gu[t * 7 + cc];
      float gn = -logf(-logf(u));
      sc[cc] = logf(pr[t][cc]) + gn;
    }
    #pragma unroll
    for (int k = 0; k < 4; ++k){
      float best = -INFINITY; int bi = 0;
      #pragma unroll
      for (int cc = 0; cc < 7; ++cc) if (sc[cc] > best){ best = sc[cc]; bi = cc; }
      sc[bi] = -INFINITY;
      out_action[t * 4 + k] = (float)bi;
      out_sel[t * 4 + k] = pr[b * 8 + bi][k];
    }
  }
}

// ---------------- L3: mfma_c1 U mark1 ----------------
__global__ __launch_bounds__(256) void k_L3(
    const float* __restrict__ x, const unsigned short* __restrict__ Wt1,
    const float* __restrict__ c1_bl, const float* __restrict__ c1_br,
    unsigned short* __restrict__ XLb, unsigned short* __restrict__ XRb, int nMfma,
    const int* __restrict__ cnt, const unsigned short* __restrict__ bucket,
    int* __restrict__ flag1, int* __restrict__ list1, int* __restrict__ n1, int N){
  int bid = blockIdx.x;
  if (bid < nMfma){
    dev_gemm_mfma<true>(bid, x, Wt1, c1_bl, c1_br, XLb, XRb);
  } else {
    dev_mark1(cnt, bucket, flag1, list1, n1, N);
  }
}

// ---------------- L4: mark2 (first 64) U gather_c1 ----------------
__global__ __launch_bounds__(256) void k_L4(
    const int* __restrict__ cnt, const unsigned short* __restrict__ bucket,
    const int* __restrict__ list1, const int* __restrict__ n1,
    int* __restrict__ flag2, int* __restrict__ list2, int* __restrict__ n2,
    const unsigned short* __restrict__ XLb, const unsigned short* __restrict__ XRb,
    const float* __restrict__ c1_att, const float* __restrict__ c1_b,
    unsigned short* __restrict__ Hb, int M){
  int bid = blockIdx.x;
  if (bid < 64){
    dev_mark2(bid, 64, cnt, bucket, list1, n1, flag2, list2, n2);
  } else {
    int gbid = bid - 64;
    int gid = (gbid * 256 + (int)threadIdx.x) >> 4;
    int l = threadIdx.x & 15;
    if (gid < M)
      dev_gather16<0>(gid, l, XLb, XRb, cnt, bucket, c1_att, c1_b,
                      nullptr, nullptr, (void*)Hb);
  }
}

// ---------------- L5: dual fp32 GEMM (512) U mfma_c2 ----------------
__global__ __launch_bounds__(256) void k_L5(
    const float* __restrict__ x,
    const float* __restrict__ a1_Wl, const float* __restrict__ a1_Wr,
    const float* __restrict__ a1_bl, const float* __restrict__ a1_br,
    float* __restrict__ XL1, float* __restrict__ XR1,
    const int* __restrict__ list1, const int* __restrict__ list2,
    const int* __restrict__ nn,
    const unsigned short* __restrict__ Hb, const unsigned short* __restrict__ Wt2,
    const float* __restrict__ c2_bl, const float* __restrict__ c2_br,
    unsigned short* __restrict__ XLb, unsigned short* __restrict__ XRb){
  __shared__ float As[64][17];
  __shared__ float Ws[16][64];
  int bid = blockIdx.x;
  if (bid < 512){
    dev_gemm_dual(bid, x, a1_Wl, a1_Wr, a1_bl, a1_br, XL1, XR1, list1, list2, nn, As, Ws);
  } else {
    dev_gemm_mfma<false>(bid - 512, Hb, Wt2, c2_bl, c2_br, XLb, XRb);
  }
}

// ---------------- L6: a1_fused (first 256, last block runs a2head) U gather_v
__global__ __launch_bounds__(256) void k_L6(
    const float* __restrict__ XL1, const float* __restrict__ XR1,
    const int* __restrict__ cnt, const unsigned short* __restrict__ bucket,
    const float* __restrict__ a1_att, const float* __restrict__ a1_b,
    const float* __restrict__ Wl7, const float* __restrict__ Wr7,
    const float* __restrict__ bl7, const float* __restrict__ br7,
    float* __restrict__ XL2, float* __restrict__ XR2,
    const int* __restrict__ list1, const int* __restrict__ n1,
    int* __restrict__ done,
    const float* __restrict__ a2_att, const float* __restrict__ a2_b,
    const float* __restrict__ gu,
    float* __restrict__ out_action, float* __restrict__ out_sel, int N,
    const unsigned short* __restrict__ XLb, const unsigned short* __restrict__ XRb,
    const float* __restrict__ c2_att, const float* __restrict__ c2_b,
    const float* __restrict__ fcW, const float* __restrict__ fcb,
    float* __restrict__ out_value, int M){
  __shared__ float pr[32][8];
  __shared__ int isLast;
  int bid = blockIdx.x;
  if (bid < 256){
    dev_a1_fused(bid, XL1, XR1, cnt, bucket, a1_att, a1_b,
                 Wl7, Wr7, bl7, br7, XL2, XR2, list1, n1);
    __syncthreads();
    if (threadIdx.x == 0){
      __threadfence();
      int v = atomicAdd(done, 1);
      isLast = (v == 255);
    }
    __syncthreads();
    if (isLast){
      __threadfence();
      dev_a2head(pr, XL2, XR2, cnt, bucket, a2_att, a2_b, gu,
                 out_action, out_sel, N);
    }
  } else {
    int gbid = bid - 256;
    int gid = (gbid * 256 + (int)threadIdx.x) >> 4;
    int l = threadIdx.x & 15;
    if (gid < M)
      dev_gather16<1>(gid, l, XLb, XRb, cnt, bucket, c2_att, c2_b,
                      fcW, fcb, (void*)out_value);
  }
}

// ---------------------------------------------------------------------------
extern "C" void kernel_launch(void* const* d_in, const int* in_sizes, int n_in,
                              void* d_out, int out_size, void* d_ws, size_t ws_size,
                              hipStream_t stream){
  const float* x  = (const float*)d_in[0];
  const int*   ei = (const int*)d_in[1];
  const float* gu = (const float*)d_in[2];
  const float* a1_Wl = (const float*)d_in[3],  *a1_bl = (const float*)d_in[4];
  const float* a1_Wr = (const float*)d_in[5],  *a1_br = (const float*)d_in[6];
  const float* a1_att= (const float*)d_in[7],  *a1_b  = (const float*)d_in[8];
  const float* a2_Wl = (const float*)d_in[9],  *a2_bl = (const float*)d_in[10];
  const float* a2_Wr = (const float*)d_in[11], *a2_br = (const float*)d_in[12];
  const float* a2_att= (const float*)d_in[13], *a2_b  = (const float*)d_in[14];
  const float* c1_Wl = (const float*)d_in[15], *c1_bl = (const float*)d_in[16];
  const float* c1_Wr = (const float*)d_in[17], *c1_br = (const float*)d_in[18];
  const float* c1_att= (const float*)d_in[19], *c1_b  = (const float*)d_in[20];
  const float* c2_Wl = (const float*)d_in[21], *c2_bl = (const float*)d_in[22];
  const float* c2_Wr = (const float*)d_in[23], *c2_br = (const float*)d_in[24];
  const float* c2_att= (const float*)d_in[25], *c2_b  = (const float*)d_in[26];
  const float* fc_W  = (const float*)d_in[27], *fc_b  = (const float*)d_in[28];

  const int M = in_sizes[0] / 128;     // 40000
  const int E = in_sizes[1] / 2;       // 640000
  const int B = in_sizes[2] / 56;      // 4
  const int N = M / B;                 // 10000
  const int nw = B * 8;                // 32
  const int T = 256;

  char* ws = (char*)d_ws;
  size_t off = 0;
  auto alloc = [&](size_t bytes) -> void* {
    void* p = ws + off;
    off += (bytes + 255) & ~(size_t)255;
    return p;
  };
  // contiguous zero region: cnt | flag1 | flag2 | nn(2) | done(1) | pad
  int*   cnt    = (int*)alloc((size_t)(3 * M + 4) * 4);
  int*   flag1  = cnt + M;
  int*   flag2  = flag1 + M;
  int*   nn     = flag2 + M;           // nn[0]=n1, nn[1]=n2, nn[2]=done
  unsigned short* bucket = (unsigned short*)alloc((size_t)M * 64 * 2);
  int*   list1  = (int*)alloc((size_t)M * 4);
  int*   list2  = (int*)alloc((size_t)M * 4);
  float* XL2    = (float*)alloc((size_t)M * 8 * 4);
  float* XR2    = (float*)alloc((size_t)M * 8 * 4);
  unsigned short* Wt1 = (unsigned short*)alloc((size_t)256 * 128 * 2);
  unsigned short* Wt2 = (unsigned short*)alloc((size_t)256 * 128 * 2);
  float* XL1 = (float*)alloc((size_t)M * 128 * 4);
  float* XR1 = (float*)alloc((size_t)M * 128 * 4);
  unsigned short* XLb = (unsigned short*)alloc((size_t)M * 128 * 2);
  unsigned short* XRb = (unsigned short*)alloc((size_t)M * 128 * 2);
  unsigned short* Hb  = (unsigned short*)alloc((size_t)M * 128 * 2);
  (void)ws_size; (void)n_in; (void)out_size;

  float* out_action = (float*)d_out;                 // 128
  float* out_sel    = out_action + (size_t)nw * 4;   // 128
  float* out_value  = out_sel + (size_t)nw * 4;      // 40000

  const int G0 = (M * 16 + T - 1) / T;               // 2500 gather blocks
  const int nMfma = M / 64;                          // 625
  const int nz = 3 * M + 4;

  // L1: zero U weight prep
  k_init<<<(nz + 65536 + T - 1) / T, T, 0, stream>>>(cnt, nz,
      c1_Wl, c1_Wr, c2_Wl, c2_Wr, Wt1, Wt2);
  // L2: scatter (1 edge/thread, ushort bucket)
  k_scatter<<<(E + T - 1) / T, T, 0, stream>>>(ei, E, cnt, bucket);
  // L3: mfma_c1 U mark1
  k_L3<<<nMfma + 1, T, 0, stream>>>(x, Wt1, c1_bl, c1_br, XLb, XRb, nMfma,
      cnt, bucket, flag1, list1, &nn[0], N);
  // L4: mark2 U gather_c1
  k_L4<<<64 + G0, T, 0, stream>>>(cnt, bucket, list1, &nn[0], flag2, list2, &nn[1],
      XLb, XRb, c1_att, c1_b, Hb, M);
  // L5: dual fp32 GEMM U mfma_c2
  k_L5<<<512 + nMfma, T, 0, stream>>>(x, a1_Wl, a1_Wr, a1_bl, a1_br,
      XL1, XR1, list1, list2, nn, Hb, Wt2, c2_bl, c2_br, XLb, XRb);
  // L6: a1_fused (+last-block a2head) U gather_v
  k_L6<<<256 + G0, T, 0, stream>>>(XL1, XR1, cnt, bucket, a1_att, a1_b,
      a2_Wl, a2_Wr, a2_bl, a2_br, XL2, XR2, list1, &nn[0], &nn[2],
      a2_att, a2_b, gu, out_action, out_sel, N,
      XLb, XRb, c2_att, c2_b, fc_W, fc_b, out_value, M);
}